// Round 7
// baseline (264.636 us; speedup 1.0000x reference)
//
#include <hip/hip_runtime.h>

#define B_ 8
#define T_ 1024
#define D_ 512
#define H_ 8
#define DK_ 64

typedef __bf16 bf16x8 __attribute__((ext_vector_type(8)));
typedef float f32x4 __attribute__((ext_vector_type(4)));

#define MFMA16(a, b, c) __builtin_amdgcn_mfma_f32_16x16x32_bf16(a, b, c, 0, 0, 0)

__device__ __forceinline__ bf16x8 pack8(float4 a, float4 b) {
  bf16x8 r;
  r[0] = (__bf16)a.x; r[1] = (__bf16)a.y; r[2] = (__bf16)a.z; r[3] = (__bf16)a.w;
  r[4] = (__bf16)b.x; r[5] = (__bf16)b.y; r[6] = (__bf16)b.z; r[7] = (__bf16)b.w;
  return r;
}

// async global->LDS DMA, 16 B per lane; lds base must be wave-uniform.
__device__ __forceinline__ void load_lds16(const void* g, void* l) {
  __builtin_amdgcn_global_load_lds(
      (const __attribute__((address_space(1))) void*)g,
      (__attribute__((address_space(3))) void*)l, 16, 0, 0);
}

// ---------------------------------------------------------------------------
// Prep: convert + transpose the 5 weight matrices to bf16 W^T[n][k],
// swizzled (key = n & 7) for the GEMM's linear B-DMA + XOR fragment reads.
// ---------------------------------------------------------------------------
__global__ __launch_bounds__(256) void cvt_w(const float* __restrict__ w0,
                                             const float* __restrict__ w1,
                                             const float* __restrict__ w2,
                                             const float* __restrict__ w3,
                                             const float* __restrict__ w4,
                                             __bf16* __restrict__ wt) {
  __shared__ float Ts[64][65];
  const float* W = (blockIdx.z == 0) ? w0
                 : (blockIdx.z == 1) ? w1
                 : (blockIdx.z == 2) ? w2
                 : (blockIdx.z == 3) ? w3 : w4;
  const int tid = threadIdx.x;
  const int kt = blockIdx.x * 64, nt = blockIdx.y * 64;
  const int r = tid >> 2, co = (tid & 3) * 16;
#pragma unroll
  for (int q = 0; q < 4; ++q)
    *(float4*)&Ts[r][co + q * 4] =
        *(const float4*)(W + (size_t)(kt + r) * 512 + nt + co + q * 4);
  __syncthreads();
  bf16x8 o0, o1;
#pragma unroll
  for (int q = 0; q < 8; ++q) o0[q] = (__bf16)Ts[co + q][r];
#pragma unroll
  for (int q = 0; q < 8; ++q) o1[q] = (__bf16)Ts[co + 8 + q][r];
  const int key = r & 7;
  __bf16* dst =
      wt + (size_t)blockIdx.z * 262144 + (size_t)(nt + r) * 512 + kt;
  *(bf16x8*)(dst + (((co >> 3) ^ key) << 3)) = o0;
  *(bf16x8*)(dst + ((((co >> 3) + 1) ^ key) << 3)) = o1;
}

// ---------------------------------------------------------------------------
// Round-7 GEMM: 128x128 tile, BK=64, **512 threads / 8 waves** (wave = 64x32
// quadrant, acc[4][2]). Rationale: r4/r5/r6 showed non-attn time pinned at
// ~161 us across three different staging schemes with 8-16 waves/CU and the
// single visible gemm0 counter row at MfmaUtil 1.3%/VALU 1.5%/occ 3.5% —
// pure latency starvation. 8-wave blocks at 34.8 KB LDS give 3 blocks/CU =
// 24 waves/CU (launch_bounds(512,6), <=85 VGPR, acc only 32) — 3x the TLP.
// PHASE 0: A = fp32 activation, reg-staged fp32->bf16 swizzled ds_write;
//   epilogues via LDS Tt[128][136], coalesced 64B/thread stores:
//   z0 quB/qvB plain, z1 kB chunk-swz(tt&7) -> d_out alias, z2 vT
//   transpose+seg-swz(d&7), z3 pB chunk-swz -> d_out alias.
// PHASE 1: A = ctx (= quB buffer, [b,h,t,dk] layout, swizzled by attn):
//   DMA with h = k0>>6; de-swizzle at fragment read (key l16&7 = t&7). out +bo.
// ---------------------------------------------------------------------------
template <int PHASE>
__global__ __launch_bounds__(512, 6) void gemm_dma(
    const float* __restrict__ qf, const float* __restrict__ kf,
    const float* __restrict__ vf, const float* __restrict__ pf,
    const __bf16* __restrict__ ctxq, const __bf16* __restrict__ Wt,
    const float* __restrict__ bq, const float* __restrict__ bk,
    const float* __restrict__ bv, const float* __restrict__ bo,
    const float* __restrict__ ub, const float* __restrict__ vb,
    __bf16* __restrict__ quB, __bf16* __restrict__ qvB,
    __bf16* __restrict__ kB, __bf16* __restrict__ vT,
    __bf16* __restrict__ pB, float* __restrict__ out) {
  __shared__ __bf16 smem[17408];  // As[8192]|Bs[8192]; epilogue Tt[128][136]
  __bf16* As = smem;              // [128][64] swizzled (key row&7)
  __bf16* Bs = smem + 8192;       // [128][64] swizzled (key row&7)
  const int tid = threadIdx.x;
  const int z = blockIdx.z;
  const int wave = tid >> 6, lane = tid & 63, l16 = lane & 15, quad = lane >> 4;
  const int wm = wave & 1, wn = wave >> 1;  // 2 x 4 wave grid
  const int m0 = blockIdx.x * 128, n0 = blockIdx.y * 128;

  const float* Af = (z == 0) ? qf : (z == 1) ? kf : (z == 2) ? vf : pf;
  const __bf16* Bg = Wt + (size_t)(PHASE ? 4 : z) * (512 * 512);

  const int drow = tid >> 3, dch = (tid & 7) * 8;   // DMA lane mapping [0,64)
  char* ldsA = (char*)As + ((tid & 448) << 4);      // wave-uniform bases
  char* ldsB = (char*)Bs + ((tid & 448) << 4);
  const int keyc = l16 & 7;                         // frag de-swizzle key
  const int arow = tid >> 2, af0 = (tid & 3) * 16;  // A reg-stage mapping
  const int ac0 = af0 >> 3;

  f32x4 acc[4][2];
#pragma unroll
  for (int rb = 0; rb < 4; ++rb)
#pragma unroll
    for (int cb = 0; cb < 2; ++cb) acc[rb][cb] = 0.f;

#pragma unroll 1
  for (int k0 = 0; k0 < 512; k0 += 64) {
    __syncthreads();  // WAR: previous iteration's fragment reads done
    load_lds16(Bg + (size_t)(n0 + drow) * 512 + k0 + dch, ldsB);
    load_lds16(Bg + (size_t)(n0 + 64 + drow) * 512 + k0 + dch, ldsB + 8192);
    if (PHASE == 1) {
      const int h1 = k0 >> 6;
      const int g0 = m0 + drow, g1 = m0 + 64 + drow;
      load_lds16(ctxq + (((size_t)((g0 >> 10) * 8 + h1)) * 1024 + (g0 & 1023)) *
                            64 + dch,
                 ldsA);
      load_lds16(ctxq + (((size_t)((g1 >> 10) * 8 + h1)) * 1024 + (g1 & 1023)) *
                            64 + dch,
                 ldsA + 8192);
    } else {
      const float* s = Af + (size_t)(m0 + arow) * 512 + k0 + af0;
      float4 a0 = *(const float4*)s;
      float4 a1 = *(const float4*)(s + 4);
      float4 a2 = *(const float4*)(s + 8);
      float4 a3 = *(const float4*)(s + 12);
      *(bf16x8*)&As[arow * 64 + ((ac0 ^ (arow & 7)) << 3)] = pack8(a0, a1);
      *(bf16x8*)&As[arow * 64 + (((ac0 + 1) ^ (arow & 7)) << 3)] = pack8(a2, a3);
    }
    __syncthreads();  // DMA drained + A ds_writes visible
#pragma unroll
    for (int s = 0; s < 2; ++s) {
      const int ph = ((s * 4 + quad) ^ keyc) << 3;
      bf16x8 afr[4], bfr[2];
#pragma unroll
      for (int rb = 0; rb < 4; ++rb)
        afr[rb] = *(const bf16x8*)&As[(wm * 64 + rb * 16 + l16) * 64 + ph];
#pragma unroll
      for (int cb = 0; cb < 2; ++cb)
        bfr[cb] = *(const bf16x8*)&Bs[(wn * 32 + cb * 16 + l16) * 64 + ph];
#pragma unroll
      for (int rb = 0; rb < 4; ++rb)
#pragma unroll
        for (int cb = 0; cb < 2; ++cb)
          acc[rb][cb] = MFMA16(afr[rb], bfr[cb], acc[rb][cb]);
    }
  }

  if (PHASE == 1) {
#pragma unroll
    for (int rb = 0; rb < 4; ++rb)
#pragma unroll
      for (int cb = 0; cb < 2; ++cb) {
        const int col = n0 + wn * 32 + cb * 16 + l16;
        const float bb = bo[col];
#pragma unroll
        for (int r = 0; r < 4; ++r) {
          const int row = m0 + wm * 64 + rb * 16 + quad * 4 + r;
          out[(size_t)row * 512 + col] = acc[rb][cb][r] + bb;
        }
      }
    return;
  }

  __syncthreads();  // all fragment reads done; smem reusable as Tt

  if (z == 2) {  // value: bias, transpose in LDS, write vT swizzled segs
    __bf16* Tt = smem;  // [128 n-local][136]
#pragma unroll
    for (int rb = 0; rb < 4; ++rb)
#pragma unroll
      for (int cb = 0; cb < 2; ++cb) {
        const int cl = wn * 32 + cb * 16 + l16;
        const float bb = bv[n0 + cl];
#pragma unroll
        for (int r = 0; r < 4; ++r) {
          const int rl = wm * 64 + rb * 16 + quad * 4 + r;
          Tt[cl * 136 + rl] = (__bf16)(acc[rb][cb][r] + bb);
        }
      }
    __syncthreads();
    const int r2 = tid >> 2;             // [0,128) n-local (dkk row)
    const int tseg = (tid & 3) >> 1;     // 64-col t segment
    const int qb = (tid & 1) * 4;        // chunk base within segment
    const int hh = (n0 + r2) >> 6, dkk = (n0 + r2) & 63;
    const int bI = m0 >> 10, t0 = m0 & 1023;
    __bf16* dst =
        vT + (((size_t)(bI * H_ + hh)) * DK_ + dkk) * T_ + t0 + tseg * 64;
    const int vkey = dkk & 7;
#pragma unroll
    for (int q = 0; q < 4; ++q) {
      const int gq = qb + q;
      *(bf16x8*)(dst + ((gq ^ vkey) * 8)) =
          *(const bf16x8*)&Tt[r2 * 136 + tseg * 64 + gq * 8];
    }
    return;
  }

  // z0/z1/z3: LDS-staged vectorized epilogue (coalesced row chunks).
  __bf16* Tt = smem;  // [128 m-local][136]
  const int trow = tid >> 2;       // [0,128) m-local
  const int cseg = tid & 3;        // 32-col segment
  const int bI = m0 >> 10, tt = (m0 & 1023) + trow;
  const int hh = (n0 >> 6) + (cseg >> 1);
  const int gqb = (cseg & 1) * 4;  // chunk base within the h's 64-col row
  const size_t obase = (((size_t)(bI * H_ + hh)) * T_ + tt) * DK_;
  const int npass = (z == 0) ? 2 : 1;
#pragma unroll 1
  for (int pass = 0; pass < npass; ++pass) {
#pragma unroll
    for (int rb = 0; rb < 4; ++rb)
#pragma unroll
      for (int cb = 0; cb < 2; ++cb) {
        const int cl = wn * 32 + cb * 16 + l16;
        const int col = n0 + cl;
        const float b0 = (z == 0) ? bq[col] : (z == 1) ? bk[col] : 0.f;
        const float b1 = (z == 0) ? (pass ? vb[col] : ub[col]) : 0.f;
#pragma unroll
        for (int r = 0; r < 4; ++r) {
          const int rl = wm * 64 + rb * 16 + quad * 4 + r;
          Tt[rl * 136 + cl] = (__bf16)((acc[rb][cb][r] + b0) + b1);
        }
      }
    __syncthreads();
    __bf16* dst = ((z == 0) ? (pass ? qvB : quB) : (z == 1) ? kB : pB) + obase;
#pragma unroll
    for (int q = 0; q < 4; ++q) {
      const int gq = gqb + q;
      const int c = (z == 0) ? gq : (gq ^ (tt & 7));  // kB/pB chunk swizzle
      *(bf16x8*)(dst + c * 8) =
          *(const bf16x8*)&Tt[trow * 136 + cseg * 32 + q * 8];
    }
    if (pass + 1 < npass) __syncthreads();
  }
}

// ---------------------------------------------------------------------------
// Fused MFMA attention — r5/r6 structure unchanged (DMA staging, pre-swizzled
// global, split-drain vmcnt(6)). Only change: ctx is now written into the
// quB BUFFER in [b,h,t,dk] layout (ctx aliases quB; each block reads its Q
// rows at kernel start and writes the same rows at kernel end — block-local,
// no cross-block hazard). gemm1 reads this layout with h = k0>>6.
// ---------------------------------------------------------------------------
__global__ __launch_bounds__(256, 4) void attn_mfma(
    const __bf16* __restrict__ qu, const __bf16* __restrict__ qv,
    const __bf16* __restrict__ kbuf, const __bf16* __restrict__ vT,
    const __bf16* __restrict__ pbuf, __bf16* __restrict__ ctx) {
  constexpr float SCALE = 0.044194173824159216f;  // 1/sqrt(512) (d_model)
  __shared__ __bf16 smemA[4488];  // Kt [64][64]; after QK^T: Rs [66][68]
  __shared__ __bf16 Vt[4096];     // V^T tile [64][64] (chunk ^ d&7)
  __shared__ __bf16 Pb[8192];     // P band [128][64] (chunk ^ (row-1)&7)
  __bf16* Kt = smemA;
  __bf16* Rs = smemA;
  __bf16* Pa = Pb;  // P weights [64][64] (chunk ^ di&7), alias band rows 0..63

  const int tid = threadIdx.x;
  const int wave = tid >> 6, lane = tid & 63, l16 = lane & 15, quad = lane >> 4;
  // XCD swizzle: g&7 = XCD slot; 8 whole (b,h) per XCD, 16 i-tiles contiguous.
  const int g = blockIdx.x;
  const int bhq = (g & 7) * 8 + (g >> 7);
  const int i0 = ((g >> 3) & 15) * 64;
  const size_t bh = (size_t)bhq * T_ * DK_;
  const __bf16* QU = qu + bh;
  const __bf16* QV = qv + bh;
  const __bf16* Kg = kbuf + bh;
  const __bf16* Vg = vT + bh;  // [DK][T]
  const __bf16* Pg = pbuf + bh;

  // A-fragments (pre-biased) held all kernel.
  bf16x8 quA[2], qvw[2], qv4[2];
  {
    const int rw = i0 + wave * 16 + l16;
    const int r4g = i0 + 64 + l16;
    const int r4 = (r4g < T_) ? r4g : T_ - 1;
#pragma unroll
    for (int s = 0; s < 2; ++s) {
      const int ko = s * 32 + quad * 8;
      quA[s] = *(const bf16x8*)&QU[(size_t)rw * DK_ + ko];
      qvw[s] = *(const bf16x8*)&QV[(size_t)rw * DK_ + ko];
      qv4[s] = *(const bf16x8*)&QV[(size_t)r4 * DK_ + ko];
    }
  }

  f32x4 Oacc[4];
#pragma unroll
  for (int cb = 0; cb < 4; ++cb) Oacc[cb] = 0.f;
  float lrun[4];
#pragma unroll
  for (int r = 0; r < 4; ++r) lrun[r] = 0.f;

  const int rbase = wave * 16 + quad * 4;
  const int keyr = l16 & 7;            // K/V/Pa de-swizzle key
  const int keyp = (l16 + 7) & 7;      // P band de-swizzle key (row-1 mod 8)
  const int drow = tid >> 3;           // DMA: row within 32-row group
  const int dch = (tid & 7) * 8;       // DMA: elem offset within row
  char* ldsK = (char*)Kt + (tid & 192) * 16;  // wave-uniform bases
  char* ldsV = (char*)Vt + (tid & 192) * 16;
  char* ldsP = (char*)Pb + (tid & 192) * 16;

#pragma unroll 1
  for (int jt = 0; jt < 16; ++jt) {
    const int j0 = jt * 64;
    int cs = T_ - 65 + j0 - i0;
    if (cs < 0) cs += T_;
    if (cs >= T_) cs -= T_;

    __syncthreads();  // previous iteration's LDS reads complete
    // ---- DMA staging. Issue order is load-bearing: K first (the 2 oldest
    // per wave), so vmcnt(6) below releases QK^T while V+P stay in flight.
    load_lds16(Kg + (size_t)(j0 + drow) * 64 + dch, ldsK);
    load_lds16(Kg + (size_t)(j0 + 32 + drow) * 64 + dch, ldsK + 4096);
    __builtin_amdgcn_sched_barrier(0);  // pin K-issue order
    load_lds16(Vg + (size_t)drow * T_ + j0 + dch, ldsV);
    load_lds16(Vg + (size_t)(32 + drow) * T_ + j0 + dch, ldsV + 4096);
#pragma unroll
    for (int c = 0; c < 4; ++c) {
      int prow = cs + c * 32 + drow;
      if (prow >= T_) prow -= T_;
      load_lds16(Pg + (size_t)prow * 64 + dch, ldsP + c * 4096);
    }
    asm volatile("s_waitcnt vmcnt(6)" ::: "memory");  // K ready
    __builtin_amdgcn_s_barrier();

    // ---- content scores S = Qu K^T (V+P DMA still in flight) ----
    f32x4 sA[4];
#pragma unroll
    for (int cb = 0; cb < 4; ++cb) sA[cb] = 0.f;
#pragma unroll
    for (int s = 0; s < 2; ++s)
#pragma unroll
      for (int cb = 0; cb < 4; ++cb) {
        bf16x8 kf = *(const bf16x8*)&Kt[(cb * 16 + l16) * 64 +
                                        (((s * 4 + quad) ^ keyr) << 3)];
        sA[cb] = MFMA16(quA[s], kf, sA[cb]);
      }

    asm volatile("s_waitcnt vmcnt(0)" ::: "memory");  // V+P ready
    __builtin_amdgcn_s_barrier();  // also: Kt reads done before Rs writes

    // ---- R band GEMM, pre-shifted store (only needed col-blocks) ----
#pragma unroll
    for (int c = 0; c < 5; ++c) {
      const int cb = 3 - wave + c;
      f32x4 rc = 0.f;
#pragma unroll
      for (int s = 0; s < 2; ++s) {
        bf16x8 pf = *(const bf16x8*)&Pb[(cb * 16 + l16) * 64 +
                                        (((s * 4 + quad) ^ keyp) << 3)];
        rc = MFMA16(qvw[s], pf, rc);
      }
      const int col = cb * 16 + l16;
#pragma unroll
      for (int rr = 0; rr < 4; ++rr) {
        const int dj = col + rbase + rr - 64;
        if (dj >= 0 && dj < 64) Rs[(rbase + rr) * 68 + dj] = (__bf16)rc[rr];
      }
    }
    {  // extra row 64 (q row i0+64), cols 0..63, one cb per wave
      const int cb = wave;
      f32x4 rc = 0.f;
#pragma unroll
      for (int s = 0; s < 2; ++s) {
        bf16x8 pf = *(const bf16x8*)&Pb[(cb * 16 + l16) * 64 +
                                        (((s * 4 + quad) ^ keyp) << 3)];
        rc = MFMA16(qv4[s], pf, rc);
      }
      if (quad == 0) Rs[64 * 68 + cb * 16 + l16] = (__bf16)rc[0];
    }
    __syncthreads();

    // ---- gather shifted pos, no-max softmax, stash P (swizzled, alias Pb) --
#pragma unroll
    for (int r = 0; r < 4; ++r) {
#pragma unroll
      for (int cb = 0; cb < 4; ++cb) {
        const int di = rbase + r;
        const int dj = cb * 16 + l16;
        const int ji = (j0 + dj) - (i0 + di);
        float pos = 0.f;
        if (ji != 1) pos = (float)Rs[(di + (ji >= 2 ? 1 : 0)) * 68 + dj];
        const float w_ = __expf((sA[cb][r] + pos) * SCALE);
        lrun[r] += w_;
        Pa[di * 64 + (dj & 7) + ((((dj >> 3) ^ di) & 7) << 3)] = (__bf16)w_;
      }
    }

    // ---- O += Pa @ V (wave-local rows; in-wave LDS ordering suffices) ----
#pragma unroll
    for (int s = 0; s < 2; ++s) {
      bf16x8 ap = *(const bf16x8*)&Pa[(wave * 16 + l16) * 64 +
                                      (((s * 4 + quad) ^ keyr) << 3)];
#pragma unroll
      for (int cb = 0; cb < 4; ++cb) {
        bf16x8 bv = *(const bf16x8*)&Vt[(cb * 16 + l16) * 64 +
                                        (((s * 4 + quad) ^ keyr) << 3)];
        Oacc[cb] = MFMA16(ap, bv, Oacc[cb]);
      }
    }
  }

  // ---- epilogue: reduce l, normalize, store ctx into quB buffer
  // ([b,h,t,dk] layout, chunk-swizzled key row&7 for gemm1's DMA). ----
  float inv[4];
#pragma unroll
  for (int r = 0; r < 4; ++r) {
    float L = lrun[r];
    L += __shfl_xor(L, 1);
    L += __shfl_xor(L, 2);
    L += __shfl_xor(L, 4);
    L += __shfl_xor(L, 8);
    inv[r] = 1.f / L;
  }
#pragma unroll
  for (int cb = 0; cb < 4; ++cb)
#pragma unroll
    for (int r = 0; r < 4; ++r) {
      const int row = i0 + rbase + r;
      const int chunk = cb * 2 + (l16 >> 3);
      const int colin = ((chunk ^ (row & 7)) << 3) + (l16 & 7);
      ctx[bh + (size_t)row * DK_ + colin] = (__bf16)(Oacc[cb][r] * inv[r]);
    }
}

// ---------------------------------------------------------------------------
extern "C" void kernel_launch(void* const* d_in, const int* in_sizes, int n_in,
                              void* d_out, int out_size, void* d_ws,
                              size_t ws_size, hipStream_t stream) {
  const float* query = (const float*)d_in[0];
  const float* key   = (const float*)d_in[1];
  const float* value = (const float*)d_in[2];
  const float* pos   = (const float*)d_in[3];
  const float* Wq = (const float*)d_in[4];
  const float* bq = (const float*)d_in[5];
  const float* Wk = (const float*)d_in[6];
  const float* bk = (const float*)d_in[7];
  const float* Wv = (const float*)d_in[8];
  const float* bv = (const float*)d_in[9];
  const float* Wp = (const float*)d_in[10];
  const float* ub = (const float*)d_in[11];
  const float* vbias = (const float*)d_in[12];
  const float* Wo = (const float*)d_in[13];
  const float* bo = (const float*)d_in[14];
  float* out = (float*)d_out;

  // ws: quB (8MB, doubles as ctx) | qvB (8MB) | vT (8MB) | Wt (2.5MB).
  // kB/pB live in d_out (16MB, dead until gemm1's final write).
  char* ws = (char*)d_ws;
  const size_t ACT = (size_t)8192 * 512 * 2;  // 8 MB
  __bf16* quB = (__bf16*)ws;                  // also ctx (aliased)
  __bf16* qvB = (__bf16*)(ws + 1 * ACT);
  __bf16* vT  = (__bf16*)(ws + 2 * ACT);
  __bf16* Wt  = (__bf16*)(ws + 3 * ACT);      // 5 x 512 KB
  __bf16* kB  = (__bf16*)d_out;
  __bf16* pB  = (__bf16*)((char*)d_out + ACT);

  cvt_w<<<dim3(8, 8, 5), 256, 0, stream>>>(Wq, Wk, Wv, Wp, Wo, Wt);

  gemm_dma<0><<<dim3(64, 4, 4), 512, 0, stream>>>(
      query, key, value, pos, nullptr, Wt, bq, bk, bv, bo, ub, vbias,
      quB, qvB, kB, vT, pB, nullptr);

  attn_mfma<<<dim3(1024), 256, 0, stream>>>(quB, qvB, kB, vT, pB, quB);

  gemm_dma<1><<<dim3(64, 4, 1), 512, 0, stream>>>(
      nullptr, nullptr, nullptr, nullptr, quB, Wt, bq, bk, bv, bo, ub, vbias,
      quB, qvB, kB, vT, pB, out);
}

// Round 8
// 245.910 us; speedup vs baseline: 1.0761x; 1.0761x over previous
//
#include <hip/hip_runtime.h>

#define B_ 8
#define T_ 1024
#define D_ 512
#define H_ 8
#define DK_ 64

typedef __bf16 bf16x8 __attribute__((ext_vector_type(8)));
typedef float f32x4 __attribute__((ext_vector_type(4)));

#define MFMA16(a, b, c) __builtin_amdgcn_mfma_f32_16x16x32_bf16(a, b, c, 0, 0, 0)

__device__ __forceinline__ bf16x8 pack8(float4 a, float4 b) {
  bf16x8 r;
  r[0] = (__bf16)a.x; r[1] = (__bf16)a.y; r[2] = (__bf16)a.z; r[3] = (__bf16)a.w;
  r[4] = (__bf16)b.x; r[5] = (__bf16)b.y; r[6] = (__bf16)b.z; r[7] = (__bf16)b.w;
  return r;
}

// async global->LDS DMA, 16 B per lane; lds base must be wave-uniform.
__device__ __forceinline__ void load_lds16(const void* g, void* l) {
  __builtin_amdgcn_global_load_lds(
      (const __attribute__((address_space(1))) void*)g,
      (__attribute__((address_space(3))) void*)l, 16, 0, 0);
}

// ---------------------------------------------------------------------------
// Prep: convert + transpose the 5 weight matrices to bf16 W^T[n][k],
// swizzled (key = n & 7) for the GEMM's linear B-DMA + XOR fragment reads.
// ---------------------------------------------------------------------------
__global__ __launch_bounds__(256) void cvt_w(const float* __restrict__ w0,
                                             const float* __restrict__ w1,
                                             const float* __restrict__ w2,
                                             const float* __restrict__ w3,
                                             const float* __restrict__ w4,
                                             __bf16* __restrict__ wt) {
  __shared__ float Ts[64][65];
  const float* W = (blockIdx.z == 0) ? w0
                 : (blockIdx.z == 1) ? w1
                 : (blockIdx.z == 2) ? w2
                 : (blockIdx.z == 3) ? w3 : w4;
  const int tid = threadIdx.x;
  const int kt = blockIdx.x * 64, nt = blockIdx.y * 64;
  const int r = tid >> 2, co = (tid & 3) * 16;
#pragma unroll
  for (int q = 0; q < 4; ++q)
    *(float4*)&Ts[r][co + q * 4] =
        *(const float4*)(W + (size_t)(kt + r) * 512 + nt + co + q * 4);
  __syncthreads();
  bf16x8 o0, o1;
#pragma unroll
  for (int q = 0; q < 8; ++q) o0[q] = (__bf16)Ts[co + q][r];
#pragma unroll
  for (int q = 0; q < 8; ++q) o1[q] = (__bf16)Ts[co + 8 + q][r];
  const int key = r & 7;
  __bf16* dst =
      wt + (size_t)blockIdx.z * 262144 + (size_t)(nt + r) * 512 + kt;
  *(bf16x8*)(dst + (((co >> 3) ^ key) << 3)) = o0;
  *(bf16x8*)(dst + ((((co >> 3) + 1) ^ key) << 3)) = o1;
}

// ---------------------------------------------------------------------------
// r5 GEMM (best-known; r6 dbuf and r7 8-wave both failed to beat it):
// 128x128 tile, BK=64, 256 thr, wave = 64x64 quadrant.
// B staged via global_load_lds(16) from pre-swizzled Wt; PHASE 0 A reg-staged
// fp32->bf16 swizzled ds_write; PHASE 1 A = ctx via DMA.
// Epilogues (PHASE 0) via LDS Tt[128][136], coalesced 128-B row chunks:
//   z0 quB/qvB plain, z1 kB chunk-swz(tt&7), z2 vT transpose+seg-swz(d&7),
//   z3 pB chunk-swz. PHASE 1: out fp32 (+bo).
// ---------------------------------------------------------------------------
template <int PHASE>
__global__ __launch_bounds__(256, 4) void gemm_dma(
    const float* __restrict__ qf, const float* __restrict__ kf,
    const float* __restrict__ vf, const float* __restrict__ pf,
    const __bf16* __restrict__ ctxA, const __bf16* __restrict__ Wt,
    const float* __restrict__ bq, const float* __restrict__ bk,
    const float* __restrict__ bv, const float* __restrict__ bo,
    const float* __restrict__ ub, const float* __restrict__ vb,
    __bf16* __restrict__ quB, __bf16* __restrict__ qvB,
    __bf16* __restrict__ kB, __bf16* __restrict__ vT,
    __bf16* __restrict__ pB, float* __restrict__ out) {
  __shared__ __bf16 smem[17408];  // As[8192] | Bs[8192]; epilogue: [128][136]
  __bf16* As = smem;
  __bf16* Bs = smem + 8192;
  const int tid = threadIdx.x;
  const int z = blockIdx.z;
  const int wave = tid >> 6, lane = tid & 63, l16 = lane & 15, quad = lane >> 4;
  const int wm = wave & 1, wn = wave >> 1;
  const int m0 = blockIdx.x * 128, n0 = blockIdx.y * 128;

  const float* Af = (z == 0) ? qf : (z == 1) ? kf : (z == 2) ? vf : pf;
  const __bf16* Bg = Wt + (size_t)(PHASE ? 4 : z) * (512 * 512);

  const int drow = tid >> 3, dch = (tid & 7) * 8;  // staging lane mapping
  char* ldsA = (char*)As + (tid & 192) * 16;       // wave-uniform bases
  char* ldsB = (char*)Bs + (tid & 192) * 16;
  const int keyc = l16 & 7;                        // frag de-swizzle key

  f32x4 acc[4][4];
#pragma unroll
  for (int rb = 0; rb < 4; ++rb)
#pragma unroll
    for (int cb = 0; cb < 4; ++cb) acc[rb][cb] = 0.f;

#pragma unroll 1
  for (int k0 = 0; k0 < 512; k0 += 64) {
    __syncthreads();  // WAR: previous iteration's fragment reads done
#pragma unroll
    for (int c4 = 0; c4 < 4; ++c4)
      load_lds16(Bg + (size_t)(n0 + c4 * 32 + drow) * 512 + k0 + dch,
                 ldsB + c4 * 4096);
    if (PHASE == 1) {
#pragma unroll
      for (int c4 = 0; c4 < 4; ++c4)
        load_lds16(ctxA + (size_t)(m0 + c4 * 32 + drow) * 512 + k0 + dch,
                   ldsA + c4 * 4096);
    } else {
      // reg-staged A: fp32 -> bf16, swizzled LDS write (key row&7)
#pragma unroll
      for (int c4 = 0; c4 < 4; ++c4) {
        const int row = c4 * 32 + drow;
        const float* s = Af + (size_t)(m0 + row) * 512 + k0 + dch;
        float4 a0 = *(const float4*)s;
        float4 a1 = *(const float4*)(s + 4);
        *(bf16x8*)&As[row * 64 + ((((dch >> 3) ^ row) & 7) << 3)] =
            pack8(a0, a1);
      }
    }
    __syncthreads();  // B-DMA drained + A ds_writes visible
#pragma unroll
    for (int s = 0; s < 2; ++s) {
      const int ph = ((s * 4 + quad) ^ keyc) << 3;
      bf16x8 afr[4], bfr[4];
#pragma unroll
      for (int rb = 0; rb < 4; ++rb)
        afr[rb] = *(const bf16x8*)&As[(wm * 64 + rb * 16 + l16) * 64 + ph];
#pragma unroll
      for (int cb = 0; cb < 4; ++cb)
        bfr[cb] = *(const bf16x8*)&Bs[(wn * 64 + cb * 16 + l16) * 64 + ph];
#pragma unroll
      for (int rb = 0; rb < 4; ++rb)
#pragma unroll
        for (int cb = 0; cb < 4; ++cb)
          acc[rb][cb] = MFMA16(afr[rb], bfr[cb], acc[rb][cb]);
    }
  }

  if (PHASE == 1) {
#pragma unroll
    for (int rb = 0; rb < 4; ++rb)
#pragma unroll
      for (int cb = 0; cb < 4; ++cb) {
        const int col = n0 + wn * 64 + cb * 16 + l16;
        const float bb = bo[col];
#pragma unroll
        for (int r = 0; r < 4; ++r) {
          const int row = m0 + wm * 64 + rb * 16 + quad * 4 + r;
          out[(size_t)row * 512 + col] = acc[rb][cb][r] + bb;
        }
      }
    return;
  }

  __syncthreads();  // all fragment reads done; smem reusable

  if (z == 2) {  // value: bias, transpose in LDS, write vT swizzled segs
    __bf16* Tt = smem;  // [128][136]
#pragma unroll
    for (int rb = 0; rb < 4; ++rb)
#pragma unroll
      for (int cb = 0; cb < 4; ++cb) {
        const int cl = wn * 64 + cb * 16 + l16;
        const float bb = bv[n0 + cl];
#pragma unroll
        for (int r = 0; r < 4; ++r) {
          const int rl = wm * 64 + rb * 16 + quad * 4 + r;
          Tt[cl * 136 + rl] = (__bf16)(acc[rb][cb][r] + bb);
        }
      }
    __syncthreads();
    const int r2 = tid >> 1, ch = (tid & 1) * 64;
    const int hh = (n0 + r2) >> 6, dkk = (n0 + r2) & 63;
    const int bI = m0 >> 10, t0 = m0 & 1023;
    __bf16* dst = vT + (((size_t)(bI * H_ + hh)) * DK_ + dkk) * T_ + t0 + ch;
    const int vkey = dkk & 7;  // chunk swizzle within each 64-col segment
#pragma unroll
    for (int q = 0; q < 8; ++q)
      *(bf16x8*)(dst + ((q ^ vkey) * 8)) =
          *(const bf16x8*)&Tt[r2 * 136 + ch + q * 8];
    return;
  }

  // z0/z1/z3: LDS-staged vectorized epilogue (coalesced 128-B row chunks).
  __bf16* Tt = smem;  // [128][136]
  const int trow = tid & 127, hs = tid >> 7;
  const int bI = m0 >> 10, tt = (m0 & 1023) + trow;
  const int hh = (n0 >> 6) + hs;
  const size_t obase = (((size_t)(bI * H_ + hh)) * T_ + tt) * DK_;
  const int npass = (z == 0) ? 2 : 1;
#pragma unroll 1
  for (int pass = 0; pass < npass; ++pass) {
#pragma unroll
    for (int rb = 0; rb < 4; ++rb)
#pragma unroll
      for (int cb = 0; cb < 4; ++cb) {
        const int cl = wn * 64 + cb * 16 + l16;
        const int col = n0 + cl;
        const float b0 = (z == 0) ? bq[col] : (z == 1) ? bk[col] : 0.f;
        const float b1 = (z == 0) ? (pass ? vb[col] : ub[col]) : 0.f;
#pragma unroll
        for (int r = 0; r < 4; ++r) {
          const int rl = wm * 64 + rb * 16 + quad * 4 + r;
          Tt[rl * 136 + cl] = (__bf16)((acc[rb][cb][r] + b0) + b1);
        }
      }
    __syncthreads();
    __bf16* dst = ((z == 0) ? (pass ? qvB : quB) : (z == 1) ? kB : pB) + obase;
#pragma unroll
    for (int qd = 0; qd < 8; ++qd) {
      const int c = (z == 0) ? qd : (qd ^ (tt & 7));  // kB/pB chunk swizzle
      *(bf16x8*)(dst + c * 8) =
          *(const bf16x8*)&Tt[trow * 136 + hs * 64 + qd * 8];
    }
    if (pass + 1 < npass) __syncthreads();
  }
}

// ---------------------------------------------------------------------------
// Fused MFMA attention — r5 structure + Round-8 VALU cuts:
//  (a) gather specialization: ji==1 only possible when delta=j0-i0 in {0,64};
//      otherwise the Rs row offset (ji>=2) is tile-uniform -> 14/16 tiles
//      drop both compares+select per element (scalar-uniform branch).
//  (b) expf -> exp2f with pre-folded SCALE*log2(e) (one fewer VALU op/elem).
//  (c) s_setprio(1) around the three MFMA clusters (T5; attn-positive m191).
// ---------------------------------------------------------------------------
__global__ __launch_bounds__(256, 4) void attn_mfma(
    const __bf16* __restrict__ qu, const __bf16* __restrict__ qv,
    const __bf16* __restrict__ kbuf, const __bf16* __restrict__ vT,
    const __bf16* __restrict__ pbuf, __bf16* __restrict__ ctx) {
  constexpr float SCALE2 = 0.06375871865f;  // 1/sqrt(512) * log2(e)
  __shared__ __bf16 smemA[4488];  // Kt [64][64]; after QK^T: Rs [66][68]
  __shared__ __bf16 Vt[4096];     // V^T tile [64][64] (chunk ^ d&7)
  __shared__ __bf16 Pb[8192];     // P band [128][64] (chunk ^ (row-1)&7)
  __bf16* Kt = smemA;
  __bf16* Rs = smemA;
  __bf16* Pa = Pb;  // P weights [64][64] (chunk ^ di&7), alias band rows 0..63

  const int tid = threadIdx.x;
  const int wave = tid >> 6, lane = tid & 63, l16 = lane & 15, quad = lane >> 4;
  // XCD swizzle: g&7 = XCD slot; 8 whole (b,h) per XCD, 16 i-tiles contiguous.
  const int g = blockIdx.x;
  const int bhq = (g & 7) * 8 + (g >> 7);
  const int i0 = ((g >> 3) & 15) * 64;
  const size_t bh = (size_t)bhq * T_ * DK_;
  const __bf16* QU = qu + bh;
  const __bf16* QV = qv + bh;
  const __bf16* Kg = kbuf + bh;
  const __bf16* Vg = vT + bh;  // [DK][T]
  const __bf16* Pg = pbuf + bh;

  // A-fragments (pre-biased) held all kernel.
  bf16x8 quA[2], qvw[2], qv4[2];
  {
    const int rw = i0 + wave * 16 + l16;
    const int r4g = i0 + 64 + l16;
    const int r4 = (r4g < T_) ? r4g : T_ - 1;
#pragma unroll
    for (int s = 0; s < 2; ++s) {
      const int ko = s * 32 + quad * 8;
      quA[s] = *(const bf16x8*)&QU[(size_t)rw * DK_ + ko];
      qvw[s] = *(const bf16x8*)&QV[(size_t)rw * DK_ + ko];
      qv4[s] = *(const bf16x8*)&QV[(size_t)r4 * DK_ + ko];
    }
  }

  f32x4 Oacc[4];
#pragma unroll
  for (int cb = 0; cb < 4; ++cb) Oacc[cb] = 0.f;
  float lrun[4];
#pragma unroll
  for (int r = 0; r < 4; ++r) lrun[r] = 0.f;

  const int rbase = wave * 16 + quad * 4;
  const int keyr = l16 & 7;            // K/V/Pa de-swizzle key
  const int keyp = (l16 + 7) & 7;      // P band de-swizzle key (row-1 mod 8)
  const int drow = tid >> 3;           // DMA: row within 32-row group
  const int dch = (tid & 7) * 8;       // DMA: elem offset within row
  char* ldsK = (char*)Kt + (tid & 192) * 16;  // wave-uniform bases
  char* ldsV = (char*)Vt + (tid & 192) * 16;
  char* ldsP = (char*)Pb + (tid & 192) * 16;

#pragma unroll 1
  for (int jt = 0; jt < 16; ++jt) {
    const int j0 = jt * 64;
    int cs = T_ - 65 + j0 - i0;
    if (cs < 0) cs += T_;
    if (cs >= T_) cs -= T_;

    __syncthreads();  // previous iteration's LDS reads complete
    // ---- DMA staging. Issue order is load-bearing: K first (the 2 oldest
    // per wave), so vmcnt(6) below releases QK^T while V+P stay in flight.
    load_lds16(Kg + (size_t)(j0 + drow) * 64 + dch, ldsK);
    load_lds16(Kg + (size_t)(j0 + 32 + drow) * 64 + dch, ldsK + 4096);
    __builtin_amdgcn_sched_barrier(0);  // pin K-issue order
    load_lds16(Vg + (size_t)drow * T_ + j0 + dch, ldsV);
    load_lds16(Vg + (size_t)(32 + drow) * T_ + j0 + dch, ldsV + 4096);
#pragma unroll
    for (int c = 0; c < 4; ++c) {
      int prow = cs + c * 32 + drow;
      if (prow >= T_) prow -= T_;
      load_lds16(Pg + (size_t)prow * 64 + dch, ldsP + c * 4096);
    }
    asm volatile("s_waitcnt vmcnt(6)" ::: "memory");  // K ready
    __builtin_amdgcn_s_barrier();

    // ---- content scores S = Qu K^T (V+P DMA still in flight) ----
    f32x4 sA[4];
#pragma unroll
    for (int cb = 0; cb < 4; ++cb) sA[cb] = 0.f;
    __builtin_amdgcn_s_setprio(1);
#pragma unroll
    for (int s = 0; s < 2; ++s)
#pragma unroll
      for (int cb = 0; cb < 4; ++cb) {
        bf16x8 kf = *(const bf16x8*)&Kt[(cb * 16 + l16) * 64 +
                                        (((s * 4 + quad) ^ keyr) << 3)];
        sA[cb] = MFMA16(quA[s], kf, sA[cb]);
      }
    __builtin_amdgcn_s_setprio(0);

    asm volatile("s_waitcnt vmcnt(0)" ::: "memory");  // V+P ready
    __builtin_amdgcn_s_barrier();  // also: Kt reads done before Rs writes

    // ---- R band GEMM, pre-shifted store (only needed col-blocks) ----
    __builtin_amdgcn_s_setprio(1);
#pragma unroll
    for (int c = 0; c < 5; ++c) {
      const int cb = 3 - wave + c;
      f32x4 rc = 0.f;
#pragma unroll
      for (int s = 0; s < 2; ++s) {
        bf16x8 pf = *(const bf16x8*)&Pb[(cb * 16 + l16) * 64 +
                                        (((s * 4 + quad) ^ keyp) << 3)];
        rc = MFMA16(qvw[s], pf, rc);
      }
      const int col = cb * 16 + l16;
#pragma unroll
      for (int rr = 0; rr < 4; ++rr) {
        const int dj = col + rbase + rr - 64;
        if (dj >= 0 && dj < 64) Rs[(rbase + rr) * 68 + dj] = (__bf16)rc[rr];
      }
    }
    {  // extra row 64 (q row i0+64), cols 0..63, one cb per wave
      const int cb = wave;
      f32x4 rc = 0.f;
#pragma unroll
      for (int s = 0; s < 2; ++s) {
        bf16x8 pf = *(const bf16x8*)&Pb[(cb * 16 + l16) * 64 +
                                        (((s * 4 + quad) ^ keyp) << 3)];
        rc = MFMA16(qv4[s], pf, rc);
      }
      if (quad == 0) Rs[64 * 68 + cb * 16 + l16] = (__bf16)rc[0];
    }
    __builtin_amdgcn_s_setprio(0);
    __syncthreads();

    // ---- gather shifted pos, no-max softmax, stash P (swizzled, alias Pb).
    // delta = j0-i0 decides the branch uniformly per tile:
    //   delta in {0,64}: ji==1 possible -> full per-element logic (2 tiles)
    //   delta >= 128: ji>=2 always -> row +1; delta <= -64: ji<=0 -> row +0.
    const int delta = j0 - i0;
    if (delta == 0 || delta == 64) {
#pragma unroll
      for (int r = 0; r < 4; ++r) {
#pragma unroll
        for (int cb = 0; cb < 4; ++cb) {
          const int di = rbase + r;
          const int dj = cb * 16 + l16;
          const int ji = delta + dj - di;
          float pos = 0.f;
          if (ji != 1) pos = (float)Rs[(di + (ji >= 2 ? 1 : 0)) * 68 + dj];
          const float w_ = exp2f((sA[cb][r] + pos) * SCALE2);
          lrun[r] += w_;
          Pa[di * 64 + (dj & 7) + ((((dj >> 3) ^ di) & 7) << 3)] = (__bf16)w_;
        }
      }
    } else {
      const int cadd = (delta >= 128) ? 1 : 0;
#pragma unroll
      for (int r = 0; r < 4; ++r) {
#pragma unroll
        for (int cb = 0; cb < 4; ++cb) {
          const int di = rbase + r;
          const int dj = cb * 16 + l16;
          const float pos = (float)Rs[(di + cadd) * 68 + dj];
          const float w_ = exp2f((sA[cb][r] + pos) * SCALE2);
          lrun[r] += w_;
          Pa[di * 64 + (dj & 7) + ((((dj >> 3) ^ di) & 7) << 3)] = (__bf16)w_;
        }
      }
    }

    // ---- O += Pa @ V (wave-local rows; in-wave LDS ordering suffices) ----
    __builtin_amdgcn_s_setprio(1);
#pragma unroll
    for (int s = 0; s < 2; ++s) {
      bf16x8 ap = *(const bf16x8*)&Pa[(wave * 16 + l16) * 64 +
                                      (((s * 4 + quad) ^ keyr) << 3)];
#pragma unroll
      for (int cb = 0; cb < 4; ++cb) {
        bf16x8 bv = *(const bf16x8*)&Vt[(cb * 16 + l16) * 64 +
                                        (((s * 4 + quad) ^ keyr) << 3)];
        Oacc[cb] = MFMA16(ap, bv, Oacc[cb]);
      }
    }
    __builtin_amdgcn_s_setprio(0);
  }

  // ---- epilogue: reduce l over 16 lanes, normalize, store ctx SWIZZLED ----
  float inv[4];
#pragma unroll
  for (int r = 0; r < 4; ++r) {
    float L = lrun[r];
    L += __shfl_xor(L, 1);
    L += __shfl_xor(L, 2);
    L += __shfl_xor(L, 4);
    L += __shfl_xor(L, 8);
    inv[r] = 1.f / L;
  }
  const int b = bhq >> 3, h = bhq & 7;
#pragma unroll
  for (int cb = 0; cb < 4; ++cb)
#pragma unroll
    for (int r = 0; r < 4; ++r) {
      const int row = i0 + rbase + r;
      const int chunk = cb * 2 + (l16 >> 3);
      const int col = h * DK_ + ((chunk ^ (row & 7)) << 3) + (l16 & 7);
      ctx[((size_t)(b * T_ + row)) * D_ + col] = (__bf16)(Oacc[cb][r] * inv[r]);
    }
}

// ---------------------------------------------------------------------------
extern "C" void kernel_launch(void* const* d_in, const int* in_sizes, int n_in,
                              void* d_out, int out_size, void* d_ws,
                              size_t ws_size, hipStream_t stream) {
  const float* query = (const float*)d_in[0];
  const float* key   = (const float*)d_in[1];
  const float* value = (const float*)d_in[2];
  const float* pos   = (const float*)d_in[3];
  const float* Wq = (const float*)d_in[4];
  const float* bq = (const float*)d_in[5];
  const float* Wk = (const float*)d_in[6];
  const float* bk = (const float*)d_in[7];
  const float* Wv = (const float*)d_in[8];
  const float* bv = (const float*)d_in[9];
  const float* Wp = (const float*)d_in[10];
  const float* ub = (const float*)d_in[11];
  const float* vbias = (const float*)d_in[12];
  const float* Wo = (const float*)d_in[13];
  const float* bo = (const float*)d_in[14];
  float* out = (float*)d_out;

  // ws: quB,qvB,kB,pB,vT,ctx (6 x 8MB) | Wt (2.5MB). (r5 layout restored.)
  char* ws = (char*)d_ws;
  const size_t ACT = (size_t)8192 * 512 * 2;  // 8 MB
  __bf16* quB = (__bf16*)ws;
  __bf16* qvB = (__bf16*)(ws + 1 * ACT);
  __bf16* kB  = (__bf16*)(ws + 2 * ACT);
  __bf16* pB  = (__bf16*)(ws + 3 * ACT);
  __bf16* vT  = (__bf16*)(ws + 4 * ACT);
  __bf16* ctx = (__bf16*)(ws + 5 * ACT);
  __bf16* Wt  = (__bf16*)(ws + 6 * ACT);      // 5 x 512 KB

  cvt_w<<<dim3(8, 8, 5), 256, 0, stream>>>(Wq, Wk, Wv, Wp, Wo, Wt);

  gemm_dma<0><<<dim3(64, 4, 4), 256, 0, stream>>>(
      query, key, value, pos, nullptr, Wt, bq, bk, bv, bo, ub, vbias,
      quB, qvB, kB, vT, pB, nullptr);

  attn_mfma<<<dim3(1024), 256, 0, stream>>>(quB, qvB, kB, vT, pB, ctx);

  gemm_dma<1><<<dim3(64, 4, 1), 256, 0, stream>>>(
      nullptr, nullptr, nullptr, nullptr, ctx, Wt, bq, bk, bv, bo, ub, vbias,
      quB, qvB, kB, vT, pB, out);
}

// Round 9
// 244.878 us; speedup vs baseline: 1.0807x; 1.0042x over previous
//
#include <hip/hip_runtime.h>

#define B_ 8
#define T_ 1024
#define D_ 512
#define H_ 8
#define DK_ 64

typedef __bf16 bf16x8 __attribute__((ext_vector_type(8)));
typedef float f32x4 __attribute__((ext_vector_type(4)));

#define MFMA16(a, b, c) __builtin_amdgcn_mfma_f32_16x16x32_bf16(a, b, c, 0, 0, 0)

__device__ __forceinline__ bf16x8 pack8(float4 a, float4 b) {
  bf16x8 r;
  r[0] = (__bf16)a.x; r[1] = (__bf16)a.y; r[2] = (__bf16)a.z; r[3] = (__bf16)a.w;
  r[4] = (__bf16)b.x; r[5] = (__bf16)b.y; r[6] = (__bf16)b.z; r[7] = (__bf16)b.w;
  return r;
}

// async global->LDS DMA, 16 B per lane; lds base must be wave-uniform.
__device__ __forceinline__ void load_lds16(const void* g, void* l) {
  __builtin_amdgcn_global_load_lds(
      (const __attribute__((address_space(1))) void*)g,
      (__attribute__((address_space(3))) void*)l, 16, 0, 0);
}

// ---------------------------------------------------------------------------
// Prep: convert + transpose the 5 weight matrices to bf16 W^T[n][k],
// swizzled (key = n & 7) for the GEMM's linear B-DMA + XOR fragment reads.
// ---------------------------------------------------------------------------
__global__ __launch_bounds__(256) void cvt_w(const float* __restrict__ w0,
                                             const float* __restrict__ w1,
                                             const float* __restrict__ w2,
                                             const float* __restrict__ w3,
                                             const float* __restrict__ w4,
                                             __bf16* __restrict__ wt) {
  __shared__ float Ts[64][65];
  const float* W = (blockIdx.z == 0) ? w0
                 : (blockIdx.z == 1) ? w1
                 : (blockIdx.z == 2) ? w2
                 : (blockIdx.z == 3) ? w3 : w4;
  const int tid = threadIdx.x;
  const int kt = blockIdx.x * 64, nt = blockIdx.y * 64;
  const int r = tid >> 2, co = (tid & 3) * 16;
#pragma unroll
  for (int q = 0; q < 4; ++q)
    *(float4*)&Ts[r][co + q * 4] =
        *(const float4*)(W + (size_t)(kt + r) * 512 + nt + co + q * 4);
  __syncthreads();
  bf16x8 o0, o1;
#pragma unroll
  for (int q = 0; q < 8; ++q) o0[q] = (__bf16)Ts[co + q][r];
#pragma unroll
  for (int q = 0; q < 8; ++q) o1[q] = (__bf16)Ts[co + 8 + q][r];
  const int key = r & 7;
  __bf16* dst =
      wt + (size_t)blockIdx.z * 262144 + (size_t)(nt + r) * 512 + kt;
  *(bf16x8*)(dst + (((co >> 3) ^ key) << 3)) = o0;
  *(bf16x8*)(dst + ((((co >> 3) + 1) ^ key) << 3)) = o1;
}

// ---------------------------------------------------------------------------
// Projection GEMM (r5/r8 best-known): 128x128 tile, BK=64, 256 thr.
// B staged via global_load_lds(16) from pre-swizzled Wt; A reg-staged
// fp32->bf16 swizzled ds_write. Epilogues via LDS Tt[128][136], coalesced
// 128-B row chunks: z0 quB/qvB plain, z1 kB chunk-swz(tt&7), z2 vT
// transpose+seg-swz(d&7), z3 pB chunk-swz.
// ---------------------------------------------------------------------------
__global__ __launch_bounds__(256, 4) void gemm_dma(
    const float* __restrict__ qf, const float* __restrict__ kf,
    const float* __restrict__ vf, const float* __restrict__ pf,
    const __bf16* __restrict__ Wt, const float* __restrict__ bq,
    const float* __restrict__ bk, const float* __restrict__ bv,
    const float* __restrict__ ub, const float* __restrict__ vb,
    __bf16* __restrict__ quB, __bf16* __restrict__ qvB,
    __bf16* __restrict__ kB, __bf16* __restrict__ vT,
    __bf16* __restrict__ pB) {
  __shared__ __bf16 smem[17408];  // As[8192] | Bs[8192]; epilogue: [128][136]
  __bf16* As = smem;
  __bf16* Bs = smem + 8192;
  const int tid = threadIdx.x;
  const int z = blockIdx.z;
  const int wave = tid >> 6, lane = tid & 63, l16 = lane & 15, quad = lane >> 4;
  const int wm = wave & 1, wn = wave >> 1;
  const int m0 = blockIdx.x * 128, n0 = blockIdx.y * 128;

  const float* Af = (z == 0) ? qf : (z == 1) ? kf : (z == 2) ? vf : pf;
  const __bf16* Bg = Wt + (size_t)z * (512 * 512);

  const int drow = tid >> 3, dch = (tid & 7) * 8;  // staging lane mapping
  char* ldsB = (char*)Bs + (tid & 192) * 16;       // wave-uniform base
  const int keyc = l16 & 7;                        // frag de-swizzle key

  f32x4 acc[4][4];
#pragma unroll
  for (int rb = 0; rb < 4; ++rb)
#pragma unroll
    for (int cb = 0; cb < 4; ++cb) acc[rb][cb] = 0.f;

#pragma unroll 1
  for (int k0 = 0; k0 < 512; k0 += 64) {
    __syncthreads();  // WAR: previous iteration's fragment reads done
#pragma unroll
    for (int c4 = 0; c4 < 4; ++c4)
      load_lds16(Bg + (size_t)(n0 + c4 * 32 + drow) * 512 + k0 + dch,
                 ldsB + c4 * 4096);
    // reg-staged A: fp32 -> bf16, swizzled LDS write (key row&7)
#pragma unroll
    for (int c4 = 0; c4 < 4; ++c4) {
      const int row = c4 * 32 + drow;
      const float* s = Af + (size_t)(m0 + row) * 512 + k0 + dch;
      float4 a0 = *(const float4*)s;
      float4 a1 = *(const float4*)(s + 4);
      *(bf16x8*)&As[row * 64 + ((((dch >> 3) ^ row) & 7) << 3)] =
          pack8(a0, a1);
    }
    __syncthreads();  // B-DMA drained + A ds_writes visible
#pragma unroll
    for (int s = 0; s < 2; ++s) {
      const int ph = ((s * 4 + quad) ^ keyc) << 3;
      bf16x8 afr[4], bfr[4];
#pragma unroll
      for (int rb = 0; rb < 4; ++rb)
        afr[rb] = *(const bf16x8*)&As[(wm * 64 + rb * 16 + l16) * 64 + ph];
#pragma unroll
      for (int cb = 0; cb < 4; ++cb)
        bfr[cb] = *(const bf16x8*)&Bs[(wn * 64 + cb * 16 + l16) * 64 + ph];
#pragma unroll
      for (int rb = 0; rb < 4; ++rb)
#pragma unroll
        for (int cb = 0; cb < 4; ++cb)
          acc[rb][cb] = MFMA16(afr[rb], bfr[cb], acc[rb][cb]);
    }
  }

  __syncthreads();  // all fragment reads done; smem reusable

  if (z == 2) {  // value: bias, transpose in LDS, write vT swizzled segs
    __bf16* Tt = smem;  // [128][136]
#pragma unroll
    for (int rb = 0; rb < 4; ++rb)
#pragma unroll
      for (int cb = 0; cb < 4; ++cb) {
        const int cl = wn * 64 + cb * 16 + l16;
        const float bb = bv[n0 + cl];
#pragma unroll
        for (int r = 0; r < 4; ++r) {
          const int rl = wm * 64 + rb * 16 + quad * 4 + r;
          Tt[cl * 136 + rl] = (__bf16)(acc[rb][cb][r] + bb);
        }
      }
    __syncthreads();
    const int r2 = tid >> 1, ch = (tid & 1) * 64;
    const int hh = (n0 + r2) >> 6, dkk = (n0 + r2) & 63;
    const int bI = m0 >> 10, t0 = m0 & 1023;
    __bf16* dst = vT + (((size_t)(bI * H_ + hh)) * DK_ + dkk) * T_ + t0 + ch;
    const int vkey = dkk & 7;  // chunk swizzle within each 64-col segment
#pragma unroll
    for (int q = 0; q < 8; ++q)
      *(bf16x8*)(dst + ((q ^ vkey) * 8)) =
          *(const bf16x8*)&Tt[r2 * 136 + ch + q * 8];
    return;
  }

  // z0/z1/z3: LDS-staged vectorized epilogue (coalesced 128-B row chunks).
  __bf16* Tt = smem;  // [128][136]
  const int trow = tid & 127, hs = tid >> 7;
  const int bI = m0 >> 10, tt = (m0 & 1023) + trow;
  const int hh = (n0 >> 6) + hs;
  const size_t obase = (((size_t)(bI * H_ + hh)) * T_ + tt) * DK_;
  const int npass = (z == 0) ? 2 : 1;
#pragma unroll 1
  for (int pass = 0; pass < npass; ++pass) {
#pragma unroll
    for (int rb = 0; rb < 4; ++rb)
#pragma unroll
      for (int cb = 0; cb < 4; ++cb) {
        const int cl = wn * 64 + cb * 16 + l16;
        const int col = n0 + cl;
        const float b0 = (z == 0) ? bq[col] : (z == 1) ? bk[col] : 0.f;
        const float b1 = (z == 0) ? (pass ? vb[col] : ub[col]) : 0.f;
#pragma unroll
        for (int r = 0; r < 4; ++r) {
          const int rl = wm * 64 + rb * 16 + quad * 4 + r;
          Tt[rl * 136 + cl] = (__bf16)((acc[rb][cb][r] + b0) + b1);
        }
      }
    __syncthreads();
    __bf16* dst = ((z == 0) ? (pass ? qvB : quB) : (z == 1) ? kB : pB) + obase;
#pragma unroll
    for (int qd = 0; qd < 8; ++qd) {
      const int c = (z == 0) ? qd : (qd ^ (tt & 7));  // kB/pB chunk swizzle
      *(bf16x8*)(dst + c * 8) =
          *(const bf16x8*)&Tt[trow * 136 + hs * 64 + qd * 8];
    }
    if (pass + 1 < npass) __syncthreads();
  }
}

// ---------------------------------------------------------------------------
// Round-9 output GEMM: out = ctx @ Wo + bo. Previous version ran a 128x128
// tile on grid (64,4) = 256 blocks = 1 block/CU = 1 wave/SIMD — zero TLP,
// every DMA drain + barrier + MFMA latency fully exposed (est. ~55-65 us for
// 4.3 GFLOP). Retiled to 64x128: grid (128,4) = 512 blocks = 2/CU =
// 2 waves/SIMD, LDS 24 KB (As 8K + Bs 16K). Wave = 64 rows x 32 cols,
// acc[4][2]. Same DMA/swizzle scheme (ctx chunk-swz key row&7; Wt
// pre-swizzled; keyc = l16&7 valid since m0 % 8 == n0 % 8 == 0).
// ---------------------------------------------------------------------------
__global__ __launch_bounds__(256, 4) void gemm_out(
    const __bf16* __restrict__ ctxA, const __bf16* __restrict__ Wo,
    const float* __restrict__ bo, float* __restrict__ out) {
  __shared__ __bf16 As[4096];   // [64][64] swizzled (key row&7)
  __shared__ __bf16 Bs[8192];   // [128][64] swizzled (key row&7)
  const int tid = threadIdx.x;
  const int wave = tid >> 6, lane = tid & 63, l16 = lane & 15, quad = lane >> 4;
  const int m0 = blockIdx.x * 64, n0 = blockIdx.y * 128;

  const int drow = tid >> 3, dch = (tid & 7) * 8;  // DMA lane mapping
  char* ldsA = (char*)As + (tid & 192) * 16;       // wave-uniform bases
  char* ldsB = (char*)Bs + (tid & 192) * 16;
  const int keyc = l16 & 7;                        // frag de-swizzle key

  f32x4 acc[4][2];
#pragma unroll
  for (int rb = 0; rb < 4; ++rb)
#pragma unroll
    for (int cb = 0; cb < 2; ++cb) acc[rb][cb] = 0.f;

#pragma unroll 1
  for (int k0 = 0; k0 < 512; k0 += 64) {
    __syncthreads();  // WAR: previous iteration's fragment reads done
#pragma unroll
    for (int c4 = 0; c4 < 2; ++c4)
      load_lds16(ctxA + (size_t)(m0 + c4 * 32 + drow) * 512 + k0 + dch,
                 ldsA + c4 * 4096);
#pragma unroll
    for (int c4 = 0; c4 < 4; ++c4)
      load_lds16(Wo + (size_t)(n0 + c4 * 32 + drow) * 512 + k0 + dch,
                 ldsB + c4 * 4096);
    __syncthreads();  // DMA drained before fragment reads
#pragma unroll
    for (int s = 0; s < 2; ++s) {
      const int ph = ((s * 4 + quad) ^ keyc) << 3;
      bf16x8 afr[4], bfr[2];
#pragma unroll
      for (int rb = 0; rb < 4; ++rb)
        afr[rb] = *(const bf16x8*)&As[(rb * 16 + l16) * 64 + ph];
#pragma unroll
      for (int cb = 0; cb < 2; ++cb)
        bfr[cb] = *(const bf16x8*)&Bs[(wave * 32 + cb * 16 + l16) * 64 + ph];
#pragma unroll
      for (int rb = 0; rb < 4; ++rb)
#pragma unroll
        for (int cb = 0; cb < 2; ++cb)
          acc[rb][cb] = MFMA16(afr[rb], bfr[cb], acc[rb][cb]);
    }
  }

#pragma unroll
  for (int rb = 0; rb < 4; ++rb)
#pragma unroll
    for (int cb = 0; cb < 2; ++cb) {
      const int col = n0 + wave * 32 + cb * 16 + l16;
      const float bb = bo[col];
#pragma unroll
      for (int r = 0; r < 4; ++r) {
        const int row = m0 + rb * 16 + quad * 4 + r;
        out[(size_t)row * 512 + col] = acc[rb][cb][r] + bb;
      }
    }
}

// ---------------------------------------------------------------------------
// Fused MFMA attention — unchanged from r8 (82.4 us steady: DMA staging,
// pre-swizzled global, split-drain vmcnt(6), uniform-tile gather, exp2f,
// setprio around MFMA clusters).
// ---------------------------------------------------------------------------
__global__ __launch_bounds__(256, 4) void attn_mfma(
    const __bf16* __restrict__ qu, const __bf16* __restrict__ qv,
    const __bf16* __restrict__ kbuf, const __bf16* __restrict__ vT,
    const __bf16* __restrict__ pbuf, __bf16* __restrict__ ctx) {
  constexpr float SCALE2 = 0.06375871865f;  // 1/sqrt(512) * log2(e)
  __shared__ __bf16 smemA[4488];  // Kt [64][64]; after QK^T: Rs [66][68]
  __shared__ __bf16 Vt[4096];     // V^T tile [64][64] (chunk ^ d&7)
  __shared__ __bf16 Pb[8192];     // P band [128][64] (chunk ^ (row-1)&7)
  __bf16* Kt = smemA;
  __bf16* Rs = smemA;
  __bf16* Pa = Pb;  // P weights [64][64] (chunk ^ di&7), alias band rows 0..63

  const int tid = threadIdx.x;
  const int wave = tid >> 6, lane = tid & 63, l16 = lane & 15, quad = lane >> 4;
  // XCD swizzle: g&7 = XCD slot; 8 whole (b,h) per XCD, 16 i-tiles contiguous.
  const int g = blockIdx.x;
  const int bhq = (g & 7) * 8 + (g >> 7);
  const int i0 = ((g >> 3) & 15) * 64;
  const size_t bh = (size_t)bhq * T_ * DK_;
  const __bf16* QU = qu + bh;
  const __bf16* QV = qv + bh;
  const __bf16* Kg = kbuf + bh;
  const __bf16* Vg = vT + bh;  // [DK][T]
  const __bf16* Pg = pbuf + bh;

  // A-fragments (pre-biased) held all kernel.
  bf16x8 quA[2], qvw[2], qv4[2];
  {
    const int rw = i0 + wave * 16 + l16;
    const int r4g = i0 + 64 + l16;
    const int r4 = (r4g < T_) ? r4g : T_ - 1;
#pragma unroll
    for (int s = 0; s < 2; ++s) {
      const int ko = s * 32 + quad * 8;
      quA[s] = *(const bf16x8*)&QU[(size_t)rw * DK_ + ko];
      qvw[s] = *(const bf16x8*)&QV[(size_t)rw * DK_ + ko];
      qv4[s] = *(const bf16x8*)&QV[(size_t)r4 * DK_ + ko];
    }
  }

  f32x4 Oacc[4];
#pragma unroll
  for (int cb = 0; cb < 4; ++cb) Oacc[cb] = 0.f;
  float lrun[4];
#pragma unroll
  for (int r = 0; r < 4; ++r) lrun[r] = 0.f;

  const int rbase = wave * 16 + quad * 4;
  const int keyr = l16 & 7;            // K/V/Pa de-swizzle key
  const int keyp = (l16 + 7) & 7;      // P band de-swizzle key (row-1 mod 8)
  const int drow = tid >> 3;           // DMA: row within 32-row group
  const int dch = (tid & 7) * 8;       // DMA: elem offset within row
  char* ldsK = (char*)Kt + (tid & 192) * 16;  // wave-uniform bases
  char* ldsV = (char*)Vt + (tid & 192) * 16;
  char* ldsP = (char*)Pb + (tid & 192) * 16;

#pragma unroll 1
  for (int jt = 0; jt < 16; ++jt) {
    const int j0 = jt * 64;
    int cs = T_ - 65 + j0 - i0;
    if (cs < 0) cs += T_;
    if (cs >= T_) cs -= T_;

    __syncthreads();  // previous iteration's LDS reads complete
    // ---- DMA staging. Issue order is load-bearing: K first (the 2 oldest
    // per wave), so vmcnt(6) below releases QK^T while V+P stay in flight.
    load_lds16(Kg + (size_t)(j0 + drow) * 64 + dch, ldsK);
    load_lds16(Kg + (size_t)(j0 + 32 + drow) * 64 + dch, ldsK + 4096);
    __builtin_amdgcn_sched_barrier(0);  // pin K-issue order
    load_lds16(Vg + (size_t)drow * T_ + j0 + dch, ldsV);
    load_lds16(Vg + (size_t)(32 + drow) * T_ + j0 + dch, ldsV + 4096);
#pragma unroll
    for (int c = 0; c < 4; ++c) {
      int prow = cs + c * 32 + drow;
      if (prow >= T_) prow -= T_;
      load_lds16(Pg + (size_t)prow * 64 + dch, ldsP + c * 4096);
    }
    asm volatile("s_waitcnt vmcnt(6)" ::: "memory");  // K ready
    __builtin_amdgcn_s_barrier();

    // ---- content scores S = Qu K^T (V+P DMA still in flight) ----
    f32x4 sA[4];
#pragma unroll
    for (int cb = 0; cb < 4; ++cb) sA[cb] = 0.f;
    __builtin_amdgcn_s_setprio(1);
#pragma unroll
    for (int s = 0; s < 2; ++s)
#pragma unroll
      for (int cb = 0; cb < 4; ++cb) {
        bf16x8 kf = *(const bf16x8*)&Kt[(cb * 16 + l16) * 64 +
                                        (((s * 4 + quad) ^ keyr) << 3)];
        sA[cb] = MFMA16(quA[s], kf, sA[cb]);
      }
    __builtin_amdgcn_s_setprio(0);

    asm volatile("s_waitcnt vmcnt(0)" ::: "memory");  // V+P ready
    __builtin_amdgcn_s_barrier();  // also: Kt reads done before Rs writes

    // ---- R band GEMM, pre-shifted store (only needed col-blocks) ----
    __builtin_amdgcn_s_setprio(1);
#pragma unroll
    for (int c = 0; c < 5; ++c) {
      const int cb = 3 - wave + c;
      f32x4 rc = 0.f;
#pragma unroll
      for (int s = 0; s < 2; ++s) {
        bf16x8 pf = *(const bf16x8*)&Pb[(cb * 16 + l16) * 64 +
                                        (((s * 4 + quad) ^ keyp) << 3)];
        rc = MFMA16(qvw[s], pf, rc);
      }
      const int col = cb * 16 + l16;
#pragma unroll
      for (int rr = 0; rr < 4; ++rr) {
        const int dj = col + rbase + rr - 64;
        if (dj >= 0 && dj < 64) Rs[(rbase + rr) * 68 + dj] = (__bf16)rc[rr];
      }
    }
    {  // extra row 64 (q row i0+64), cols 0..63, one cb per wave
      const int cb = wave;
      f32x4 rc = 0.f;
#pragma unroll
      for (int s = 0; s < 2; ++s) {
        bf16x8 pf = *(const bf16x8*)&Pb[(cb * 16 + l16) * 64 +
                                        (((s * 4 + quad) ^ keyp) << 3)];
        rc = MFMA16(qv4[s], pf, rc);
      }
      if (quad == 0) Rs[64 * 68 + cb * 16 + l16] = (__bf16)rc[0];
    }
    __builtin_amdgcn_s_setprio(0);
    __syncthreads();

    // ---- gather shifted pos, no-max softmax, stash P (swizzled, alias Pb).
    // delta = j0-i0 decides the branch uniformly per tile:
    //   delta in {0,64}: ji==1 possible -> full per-element logic (2 tiles)
    //   delta >= 128: ji>=2 always -> row +1; delta <= -64: ji<=0 -> row +0.
    const int delta = j0 - i0;
    if (delta == 0 || delta == 64) {
#pragma unroll
      for (int r = 0; r < 4; ++r) {
#pragma unroll
        for (int cb = 0; cb < 4; ++cb) {
          const int di = rbase + r;
          const int dj = cb * 16 + l16;
          const int ji = delta + dj - di;
          float pos = 0.f;
          if (ji != 1) pos = (float)Rs[(di + (ji >= 2 ? 1 : 0)) * 68 + dj];
          const float w_ = exp2f((sA[cb][r] + pos) * SCALE2);
          lrun[r] += w_;
          Pa[di * 64 + (dj & 7) + ((((dj >> 3) ^ di) & 7) << 3)] = (__bf16)w_;
        }
      }
    } else {
      const int cadd = (delta >= 128) ? 1 : 0;
#pragma unroll
      for (int r = 0; r < 4; ++r) {
#pragma unroll
        for (int cb = 0; cb < 4; ++cb) {
          const int di = rbase + r;
          const int dj = cb * 16 + l16;
          const float pos = (float)Rs[(di + cadd) * 68 + dj];
          const float w_ = exp2f((sA[cb][r] + pos) * SCALE2);
          lrun[r] += w_;
          Pa[di * 64 + (dj & 7) + ((((dj >> 3) ^ di) & 7) << 3)] = (__bf16)w_;
        }
      }
    }

    // ---- O += Pa @ V (wave-local rows; in-wave LDS ordering suffices) ----
    __builtin_amdgcn_s_setprio(1);
#pragma unroll
    for (int s = 0; s < 2; ++s) {
      bf16x8 ap = *(const bf16x8*)&Pa[(wave * 16 + l16) * 64 +
                                      (((s * 4 + quad) ^ keyr) << 3)];
#pragma unroll
      for (int cb = 0; cb < 4; ++cb) {
        bf16x8 bv = *(const bf16x8*)&Vt[(cb * 16 + l16) * 64 +
                                        (((s * 4 + quad) ^ keyr) << 3)];
        Oacc[cb] = MFMA16(ap, bv, Oacc[cb]);
      }
    }
    __builtin_amdgcn_s_setprio(0);
  }

  // ---- epilogue: reduce l over 16 lanes, normalize, store ctx SWIZZLED ----
  float inv[4];
#pragma unroll
  for (int r = 0; r < 4; ++r) {
    float L = lrun[r];
    L += __shfl_xor(L, 1);
    L += __shfl_xor(L, 2);
    L += __shfl_xor(L, 4);
    L += __shfl_xor(L, 8);
    inv[r] = 1.f / L;
  }
  const int b = bhq >> 3, h = bhq & 7;
#pragma unroll
  for (int cb = 0; cb < 4; ++cb)
#pragma unroll
    for (int r = 0; r < 4; ++r) {
      const int row = i0 + rbase + r;
      const int chunk = cb * 2 + (l16 >> 3);
      const int col = h * DK_ + ((chunk ^ (row & 7)) << 3) + (l16 & 7);
      ctx[((size_t)(b * T_ + row)) * D_ + col] = (__bf16)(Oacc[cb][r] * inv[r]);
    }
}

// ---------------------------------------------------------------------------
extern "C" void kernel_launch(void* const* d_in, const int* in_sizes, int n_in,
                              void* d_out, int out_size, void* d_ws,
                              size_t ws_size, hipStream_t stream) {
  const float* query = (const float*)d_in[0];
  const float* key   = (const float*)d_in[1];
  const float* value = (const float*)d_in[2];
  const float* pos   = (const float*)d_in[3];
  const float* Wq = (const float*)d_in[4];
  const float* bq = (const float*)d_in[5];
  const float* Wk = (const float*)d_in[6];
  const float* bk = (const float*)d_in[7];
  const float* Wv = (const float*)d_in[8];
  const float* bv = (const float*)d_in[9];
  const float* Wp = (const float*)d_in[10];
  const float* ub = (const float*)d_in[11];
  const float* vbias = (const float*)d_in[12];
  const float* Wo = (const float*)d_in[13];
  const float* bo = (const float*)d_in[14];
  float* out = (float*)d_out;

  // ws: quB,qvB,kB,pB,vT,ctx (6 x 8MB) | Wt (2.5MB). (r8 layout.)
  char* ws = (char*)d_ws;
  const size_t ACT = (size_t)8192 * 512 * 2;  // 8 MB
  __bf16* quB = (__bf16*)ws;
  __bf16* qvB = (__bf16*)(ws + 1 * ACT);
  __bf16* kB  = (__bf16*)(ws + 2 * ACT);
  __bf16* pB  = (__bf16*)(ws + 3 * ACT);
  __bf16* vT  = (__bf16*)(ws + 4 * ACT);
  __bf16* ctx = (__bf16*)(ws + 5 * ACT);
  __bf16* Wt  = (__bf16*)(ws + 6 * ACT);      // 5 x 512 KB

  cvt_w<<<dim3(8, 8, 5), 256, 0, stream>>>(Wq, Wk, Wv, Wp, Wo, Wt);

  gemm_dma<<<dim3(64, 4, 4), 256, 0, stream>>>(
      query, key, value, pos, Wt, bq, bk, bv, ub, vbias,
      quB, qvB, kB, vT, pB);

  attn_mfma<<<dim3(1024), 256, 0, stream>>>(quB, qvB, kB, vT, pB, ctx);

  gemm_out<<<dim3(128, 4), 256, 0, stream>>>(ctx, Wt + 4 * 262144, bo, out);
}

// Round 10
// 243.454 us; speedup vs baseline: 1.0870x; 1.0058x over previous
//
#include <hip/hip_runtime.h>

#define B_ 8
#define T_ 1024
#define D_ 512
#define H_ 8
#define DK_ 64

typedef __bf16 bf16x8 __attribute__((ext_vector_type(8)));
typedef float f32x4 __attribute__((ext_vector_type(4)));

#define MFMA16(a, b, c) __builtin_amdgcn_mfma_f32_16x16x32_bf16(a, b, c, 0, 0, 0)

__device__ __forceinline__ bf16x8 pack8(float4 a, float4 b) {
  bf16x8 r;
  r[0] = (__bf16)a.x; r[1] = (__bf16)a.y; r[2] = (__bf16)a.z; r[3] = (__bf16)a.w;
  r[4] = (__bf16)b.x; r[5] = (__bf16)b.y; r[6] = (__bf16)b.z; r[7] = (__bf16)b.w;
  return r;
}

// async global->LDS DMA, 16 B per lane; lds base must be wave-uniform.
__device__ __forceinline__ void load_lds16(const void* g, void* l) {
  __builtin_amdgcn_global_load_lds(
      (const __attribute__((address_space(1))) void*)g,
      (__attribute__((address_space(3))) void*)l, 16, 0, 0);
}

// ---------------------------------------------------------------------------
// Prep: convert + transpose the 5 weight matrices to bf16 W^T[n][k],
// swizzled (key = n & 7) for the GEMM's linear B-DMA + XOR fragment reads.
// ---------------------------------------------------------------------------
__global__ __launch_bounds__(256) void cvt_w(const float* __restrict__ w0,
                                             const float* __restrict__ w1,
                                             const float* __restrict__ w2,
                                             const float* __restrict__ w3,
                                             const float* __restrict__ w4,
                                             __bf16* __restrict__ wt) {
  __shared__ float Ts[64][65];
  const float* W = (blockIdx.z == 0) ? w0
                 : (blockIdx.z == 1) ? w1
                 : (blockIdx.z == 2) ? w2
                 : (blockIdx.z == 3) ? w3 : w4;
  const int tid = threadIdx.x;
  const int kt = blockIdx.x * 64, nt = blockIdx.y * 64;
  const int r = tid >> 2, co = (tid & 3) * 16;
#pragma unroll
  for (int q = 0; q < 4; ++q)
    *(float4*)&Ts[r][co + q * 4] =
        *(const float4*)(W + (size_t)(kt + r) * 512 + nt + co + q * 4);
  __syncthreads();
  bf16x8 o0, o1;
#pragma unroll
  for (int q = 0; q < 8; ++q) o0[q] = (__bf16)Ts[co + q][r];
#pragma unroll
  for (int q = 0; q < 8; ++q) o1[q] = (__bf16)Ts[co + 8 + q][r];
  const int key = r & 7;
  __bf16* dst =
      wt + (size_t)blockIdx.z * 262144 + (size_t)(nt + r) * 512 + kt;
  *(bf16x8*)(dst + (((co >> 3) ^ key) << 3)) = o0;
  *(bf16x8*)(dst + ((((co >> 3) + 1) ^ key) << 3)) = o1;
}

// ---------------------------------------------------------------------------
// Round-10 projection GEMM: counted-vmcnt pipeline (real T4 — r6's dbuf used
// __syncthreads whose implicit vmcnt(0) drained the prefetch it tried to
// keep in flight). A double-buffered in LDS (reg-staged pack), B single
// buffer. Per iter: raw s_barrier (WAR; LDS reads already retired at wave's
// MFMA) -> pack A(k) (compiler drains only A(k)'s own loads) -> issue B-DMA(k)
// -> issue A-loads(k+1) to regs -> s_waitcnt vmcnt(4) lgkmcnt(0) (B(k) done,
// packs published, A(k+1) STAYS IN FLIGHT across the barrier) -> raw
// s_barrier -> MFMA. Only B's L2 latency is exposed; A's HBM latency spans a
// full iteration. LDS 48 KB -> 3 blocks/CU; launch_bounds(256,3) -> ~170-reg
// cap, no spill for ~128-reg demand. Epilogues unchanged from r8.
// ---------------------------------------------------------------------------
__global__ __launch_bounds__(256, 3) void gemm_dma(
    const float* __restrict__ qf, const float* __restrict__ kf,
    const float* __restrict__ vf, const float* __restrict__ pf,
    const __bf16* __restrict__ Wt, const float* __restrict__ bq,
    const float* __restrict__ bk, const float* __restrict__ bv,
    const float* __restrict__ ub, const float* __restrict__ vb,
    __bf16* __restrict__ quB, __bf16* __restrict__ qvB,
    __bf16* __restrict__ kB, __bf16* __restrict__ vT,
    __bf16* __restrict__ pB) {
  __shared__ __bf16 smem[24576];  // As dbuf [2][8192] | Bs [8192]; Tt aliases
  __bf16* As = smem;              // [2][128][64] swizzled (key row&7)
  __bf16* Bs = smem + 16384;      // [128][64] swizzled (key row&7)
  const int tid = threadIdx.x;
  const int z = blockIdx.z;
  const int wave = tid >> 6, lane = tid & 63, l16 = lane & 15, quad = lane >> 4;
  const int wm = wave & 1, wn = wave >> 1;
  const int m0 = blockIdx.x * 128, n0 = blockIdx.y * 128;

  const float* Af = (z == 0) ? qf : (z == 1) ? kf : (z == 2) ? vf : pf;
  const __bf16* Bg = Wt + (size_t)z * (512 * 512);

  const int drow = tid >> 3, dch = (tid & 7) * 8;  // staging lane mapping
  char* ldsB = (char*)Bs + (tid & 192) * 16;       // wave-uniform base
  const int keyc = l16 & 7;                        // frag de-swizzle key
  const int arow_sw = ((((dch >> 3)) & 7) << 3);   // (chunk ^ row) applied below

  f32x4 acc[4][4];
#pragma unroll
  for (int rb = 0; rb < 4; ++rb)
#pragma unroll
    for (int cb = 0; cb < 4; ++cb) acc[rb][cb] = 0.f;

  float4 pa[4][2];  // in-flight A tile (32 VGPR)
  // prologue: A(0) -> regs
#pragma unroll
  for (int c4 = 0; c4 < 4; ++c4) {
    const float* s = Af + (size_t)(m0 + c4 * 32 + drow) * 512 + dch;
    pa[c4][0] = *(const float4*)s;
    pa[c4][1] = *(const float4*)(s + 4);
  }

#pragma unroll 1
  for (int k0 = 0; k0 < 512; k0 += 64) {
    const int cur = (k0 >> 6) & 1;
    __builtin_amdgcn_s_barrier();  // WAR: Bs + As[cur] reads retired

    // pack A(k) from regs -> As[cur] (compiler waits only A(k)'s loads)
#pragma unroll
    for (int c4 = 0; c4 < 4; ++c4) {
      const int row = c4 * 32 + drow;
      *(bf16x8*)&As[cur * 8192 + row * 64 + ((((dch >> 3) ^ row) & 7) << 3)] =
          pack8(pa[c4][0], pa[c4][1]);
    }
    __builtin_amdgcn_sched_barrier(0);
    // B DMA(k) -> Bs
#pragma unroll
    for (int c4 = 0; c4 < 4; ++c4)
      load_lds16(Bg + (size_t)(n0 + c4 * 32 + drow) * 512 + k0 + dch,
                 ldsB + c4 * 4096);
    __builtin_amdgcn_sched_barrier(0);
    if (k0 + 64 < 512) {
      // A-loads(k+1) -> regs; stay in flight across the barrier
#pragma unroll
      for (int c4 = 0; c4 < 4; ++c4) {
        const float* s = Af + (size_t)(m0 + c4 * 32 + drow) * 512 + k0 + 64 + dch;
        pa[c4][0] = *(const float4*)s;
        pa[c4][1] = *(const float4*)(s + 4);
      }
      __builtin_amdgcn_sched_barrier(0);
      asm volatile("s_waitcnt vmcnt(4) lgkmcnt(0)" ::: "memory");  // B done
    } else {
      asm volatile("s_waitcnt vmcnt(0) lgkmcnt(0)" ::: "memory");
    }
    __builtin_amdgcn_s_barrier();

#pragma unroll
    for (int s = 0; s < 2; ++s) {
      const int ph = ((s * 4 + quad) ^ keyc) << 3;
      bf16x8 afr[4], bfr[4];
#pragma unroll
      for (int rb = 0; rb < 4; ++rb)
        afr[rb] = *(const bf16x8*)&As[cur * 8192 +
                                      (wm * 64 + rb * 16 + l16) * 64 + ph];
#pragma unroll
      for (int cb = 0; cb < 4; ++cb)
        bfr[cb] = *(const bf16x8*)&Bs[(wn * 64 + cb * 16 + l16) * 64 + ph];
#pragma unroll
      for (int rb = 0; rb < 4; ++rb)
#pragma unroll
        for (int cb = 0; cb < 4; ++cb)
          acc[rb][cb] = MFMA16(afr[rb], bfr[cb], acc[rb][cb]);
    }
  }

  __syncthreads();  // all fragment reads done; smem reusable

  if (z == 2) {  // value: bias, transpose in LDS, write vT swizzled segs
    __bf16* Tt = smem;  // [128][136]
#pragma unroll
    for (int rb = 0; rb < 4; ++rb)
#pragma unroll
      for (int cb = 0; cb < 4; ++cb) {
        const int cl = wn * 64 + cb * 16 + l16;
        const float bb = bv[n0 + cl];
#pragma unroll
        for (int r = 0; r < 4; ++r) {
          const int rl = wm * 64 + rb * 16 + quad * 4 + r;
          Tt[cl * 136 + rl] = (__bf16)(acc[rb][cb][r] + bb);
        }
      }
    __syncthreads();
    const int r2 = tid >> 1, ch = (tid & 1) * 64;
    const int hh = (n0 + r2) >> 6, dkk = (n0 + r2) & 63;
    const int bI = m0 >> 10, t0 = m0 & 1023;
    __bf16* dst = vT + (((size_t)(bI * H_ + hh)) * DK_ + dkk) * T_ + t0 + ch;
    const int vkey = dkk & 7;  // chunk swizzle within each 64-col segment
#pragma unroll
    for (int q = 0; q < 8; ++q)
      *(bf16x8*)(dst + ((q ^ vkey) * 8)) =
          *(const bf16x8*)&Tt[r2 * 136 + ch + q * 8];
    return;
  }

  // z0/z1/z3: LDS-staged vectorized epilogue (coalesced 128-B row chunks).
  __bf16* Tt = smem;  // [128][136]
  const int trow = tid & 127, hs = tid >> 7;
  const int bI = m0 >> 10, tt = (m0 & 1023) + trow;
  const int hh = (n0 >> 6) + hs;
  const size_t obase = (((size_t)(bI * H_ + hh)) * T_ + tt) * DK_;
  const int npass = (z == 0) ? 2 : 1;
#pragma unroll 1
  for (int pass = 0; pass < npass; ++pass) {
#pragma unroll
    for (int rb = 0; rb < 4; ++rb)
#pragma unroll
      for (int cb = 0; cb < 4; ++cb) {
        const int cl = wn * 64 + cb * 16 + l16;
        const int col = n0 + cl;
        const float b0 = (z == 0) ? bq[col] : (z == 1) ? bk[col] : 0.f;
        const float b1 = (z == 0) ? (pass ? vb[col] : ub[col]) : 0.f;
#pragma unroll
        for (int r = 0; r < 4; ++r) {
          const int rl = wm * 64 + rb * 16 + quad * 4 + r;
          Tt[rl * 136 + cl] = (__bf16)((acc[rb][cb][r] + b0) + b1);
        }
      }
    __syncthreads();
    __bf16* dst = ((z == 0) ? (pass ? qvB : quB) : (z == 1) ? kB : pB) + obase;
#pragma unroll
    for (int qd = 0; qd < 8; ++qd) {
      const int c = (z == 0) ? qd : (qd ^ (tt & 7));  // kB/pB chunk swizzle
      *(bf16x8*)(dst + c * 8) =
          *(const bf16x8*)&Tt[trow * 136 + hs * 64 + qd * 8];
    }
    if (pass + 1 < npass) __syncthreads();
  }
}

// ---------------------------------------------------------------------------
// Round-10 output GEMM: 64x128 tile (r9 grid: 512 blocks = 2/CU), now fully
// double-buffered with counted vmcnt: per iter issue next tile's 6 DMAs,
// steady-state wait vmcnt(6) (12 outstanding -> drain the 6 oldest = this
// tile), vmcnt(0) only on the last iteration. Raw barriers (no implicit
// full drain). LDS 48 KB dbuf.
// ---------------------------------------------------------------------------
__global__ __launch_bounds__(256, 2) void gemm_out(
    const __bf16* __restrict__ ctxA, const __bf16* __restrict__ Wo,
    const float* __restrict__ bo, float* __restrict__ out) {
  __shared__ __bf16 As[2][4096];  // [64][64] swizzled (key row&7)
  __shared__ __bf16 Bs[2][8192];  // [128][64] swizzled (key row&7)
  const int tid = threadIdx.x;
  const int wave = tid >> 6, lane = tid & 63, l16 = lane & 15, quad = lane >> 4;
  const int m0 = blockIdx.x * 64, n0 = blockIdx.y * 128;

  const int drow = tid >> 3, dch = (tid & 7) * 8;  // DMA lane mapping
  char* ldsA = (char*)As + (tid & 192) * 16;       // wave-uniform bases
  char* ldsB = (char*)Bs + (tid & 192) * 16;
  const int keyc = l16 & 7;                        // frag de-swizzle key

  f32x4 acc[4][2];
#pragma unroll
  for (int rb = 0; rb < 4; ++rb)
#pragma unroll
    for (int cb = 0; cb < 2; ++cb) acc[rb][cb] = 0.f;

#define GO_ISSUE(KK, BUF)                                                     \
  {                                                                           \
    _Pragma("unroll") for (int c4 = 0; c4 < 2; ++c4)                          \
        load_lds16(ctxA + (size_t)(m0 + c4 * 32 + drow) * 512 + (KK) + dch,   \
                   ldsA + (BUF) * 8192 + c4 * 4096);                          \
    _Pragma("unroll") for (int c4 = 0; c4 < 4; ++c4)                          \
        load_lds16(Wo + (size_t)(n0 + c4 * 32 + drow) * 512 + (KK) + dch,     \
                   ldsB + (BUF) * 16384 + c4 * 4096);                         \
  }

  GO_ISSUE(0, 0)  // prologue: tile 0 in flight

#pragma unroll 1
  for (int k0 = 0; k0 < 512; k0 += 64) {
    const int cur = (k0 >> 6) & 1;
    __builtin_amdgcn_s_barrier();  // WAR: buf[cur^1] reads retired
    if (k0 + 64 < 512) {
      GO_ISSUE(k0 + 64, cur ^ 1)
      __builtin_amdgcn_sched_barrier(0);
      asm volatile("s_waitcnt vmcnt(6)" ::: "memory");  // tile k drained
    } else {
      asm volatile("s_waitcnt vmcnt(0)" ::: "memory");
    }
    __builtin_amdgcn_s_barrier();

#pragma unroll
    for (int s = 0; s < 2; ++s) {
      const int ph = ((s * 4 + quad) ^ keyc) << 3;
      bf16x8 afr[4], bfr[2];
#pragma unroll
      for (int rb = 0; rb < 4; ++rb)
        afr[rb] = *(const bf16x8*)&As[cur][(rb * 16 + l16) * 64 + ph];
#pragma unroll
      for (int cb = 0; cb < 2; ++cb)
        bfr[cb] = *(const bf16x8*)&Bs[cur][(wave * 32 + cb * 16 + l16) * 64 + ph];
#pragma unroll
      for (int rb = 0; rb < 4; ++rb)
#pragma unroll
        for (int cb = 0; cb < 2; ++cb)
          acc[rb][cb] = MFMA16(afr[rb], bfr[cb], acc[rb][cb]);
    }
  }

#pragma unroll
  for (int rb = 0; rb < 4; ++rb)
#pragma unroll
    for (int cb = 0; cb < 2; ++cb) {
      const int col = n0 + wave * 32 + cb * 16 + l16;
      const float bb = bo[col];
#pragma unroll
      for (int r = 0; r < 4; ++r) {
        const int row = m0 + rb * 16 + quad * 4 + r;
        out[(size_t)row * 512 + col] = acc[rb][cb][r] + bb;
      }
    }
}

// ---------------------------------------------------------------------------
// Fused MFMA attention — unchanged from r8 (82-84 us steady: DMA staging,
// pre-swizzled global, split-drain vmcnt(6), uniform-tile gather, exp2f,
// setprio around MFMA clusters).
// ---------------------------------------------------------------------------
__global__ __launch_bounds__(256, 4) void attn_mfma(
    const __bf16* __restrict__ qu, const __bf16* __restrict__ qv,
    const __bf16* __restrict__ kbuf, const __bf16* __restrict__ vT,
    const __bf16* __restrict__ pbuf, __bf16* __restrict__ ctx) {
  constexpr float SCALE2 = 0.06375871865f;  // 1/sqrt(512) * log2(e)
  __shared__ __bf16 smemA[4488];  // Kt [64][64]; after QK^T: Rs [66][68]
  __shared__ __bf16 Vt[4096];     // V^T tile [64][64] (chunk ^ d&7)
  __shared__ __bf16 Pb[8192];     // P band [128][64] (chunk ^ (row-1)&7)
  __bf16* Kt = smemA;
  __bf16* Rs = smemA;
  __bf16* Pa = Pb;  // P weights [64][64] (chunk ^ di&7), alias band rows 0..63

  const int tid = threadIdx.x;
  const int wave = tid >> 6, lane = tid & 63, l16 = lane & 15, quad = lane >> 4;
  // XCD swizzle: g&7 = XCD slot; 8 whole (b,h) per XCD, 16 i-tiles contiguous.
  const int g = blockIdx.x;
  const int bhq = (g & 7) * 8 + (g >> 7);
  const int i0 = ((g >> 3) & 15) * 64;
  const size_t bh = (size_t)bhq * T_ * DK_;
  const __bf16* QU = qu + bh;
  const __bf16* QV = qv + bh;
  const __bf16* Kg = kbuf + bh;
  const __bf16* Vg = vT + bh;  // [DK][T]
  const __bf16* Pg = pbuf + bh;

  // A-fragments (pre-biased) held all kernel.
  bf16x8 quA[2], qvw[2], qv4[2];
  {
    const int rw = i0 + wave * 16 + l16;
    const int r4g = i0 + 64 + l16;
    const int r4 = (r4g < T_) ? r4g : T_ - 1;
#pragma unroll
    for (int s = 0; s < 2; ++s) {
      const int ko = s * 32 + quad * 8;
      quA[s] = *(const bf16x8*)&QU[(size_t)rw * DK_ + ko];
      qvw[s] = *(const bf16x8*)&QV[(size_t)rw * DK_ + ko];
      qv4[s] = *(const bf16x8*)&QV[(size_t)r4 * DK_ + ko];
    }
  }

  f32x4 Oacc[4];
#pragma unroll
  for (int cb = 0; cb < 4; ++cb) Oacc[cb] = 0.f;
  float lrun[4];
#pragma unroll
  for (int r = 0; r < 4; ++r) lrun[r] = 0.f;

  const int rbase = wave * 16 + quad * 4;
  const int keyr = l16 & 7;            // K/V/Pa de-swizzle key
  const int keyp = (l16 + 7) & 7;      // P band de-swizzle key (row-1 mod 8)
  const int drow = tid >> 3;           // DMA: row within 32-row group
  const int dch = (tid & 7) * 8;       // DMA: elem offset within row
  char* ldsK = (char*)Kt + (tid & 192) * 16;  // wave-uniform bases
  char* ldsV = (char*)Vt + (tid & 192) * 16;
  char* ldsP = (char*)Pb + (tid & 192) * 16;

#pragma unroll 1
  for (int jt = 0; jt < 16; ++jt) {
    const int j0 = jt * 64;
    int cs = T_ - 65 + j0 - i0;
    if (cs < 0) cs += T_;
    if (cs >= T_) cs -= T_;

    __syncthreads();  // previous iteration's LDS reads complete
    // ---- DMA staging. Issue order is load-bearing: K first (the 2 oldest
    // per wave), so vmcnt(6) below releases QK^T while V+P stay in flight.
    load_lds16(Kg + (size_t)(j0 + drow) * 64 + dch, ldsK);
    load_lds16(Kg + (size_t)(j0 + 32 + drow) * 64 + dch, ldsK + 4096);
    __builtin_amdgcn_sched_barrier(0);  // pin K-issue order
    load_lds16(Vg + (size_t)drow * T_ + j0 + dch, ldsV);
    load_lds16(Vg + (size_t)(32 + drow) * T_ + j0 + dch, ldsV + 4096);
#pragma unroll
    for (int c = 0; c < 4; ++c) {
      int prow = cs + c * 32 + drow;
      if (prow >= T_) prow -= T_;
      load_lds16(Pg + (size_t)prow * 64 + dch, ldsP + c * 4096);
    }
    asm volatile("s_waitcnt vmcnt(6)" ::: "memory");  // K ready
    __builtin_amdgcn_s_barrier();

    // ---- content scores S = Qu K^T (V+P DMA still in flight) ----
    f32x4 sA[4];
#pragma unroll
    for (int cb = 0; cb < 4; ++cb) sA[cb] = 0.f;
    __builtin_amdgcn_s_setprio(1);
#pragma unroll
    for (int s = 0; s < 2; ++s)
#pragma unroll
      for (int cb = 0; cb < 4; ++cb) {
        bf16x8 kf = *(const bf16x8*)&Kt[(cb * 16 + l16) * 64 +
                                        (((s * 4 + quad) ^ keyr) << 3)];
        sA[cb] = MFMA16(quA[s], kf, sA[cb]);
      }
    __builtin_amdgcn_s_setprio(0);

    asm volatile("s_waitcnt vmcnt(0)" ::: "memory");  // V+P ready
    __builtin_amdgcn_s_barrier();  // also: Kt reads done before Rs writes

    // ---- R band GEMM, pre-shifted store (only needed col-blocks) ----
    __builtin_amdgcn_s_setprio(1);
#pragma unroll
    for (int c = 0; c < 5; ++c) {
      const int cb = 3 - wave + c;
      f32x4 rc = 0.f;
#pragma unroll
      for (int s = 0; s < 2; ++s) {
        bf16x8 pf = *(const bf16x8*)&Pb[(cb * 16 + l16) * 64 +
                                        (((s * 4 + quad) ^ keyp) << 3)];
        rc = MFMA16(qvw[s], pf, rc);
      }
      const int col = cb * 16 + l16;
#pragma unroll
      for (int rr = 0; rr < 4; ++rr) {
        const int dj = col + rbase + rr - 64;
        if (dj >= 0 && dj < 64) Rs[(rbase + rr) * 68 + dj] = (__bf16)rc[rr];
      }
    }
    {  // extra row 64 (q row i0+64), cols 0..63, one cb per wave
      const int cb = wave;
      f32x4 rc = 0.f;
#pragma unroll
      for (int s = 0; s < 2; ++s) {
        bf16x8 pf = *(const bf16x8*)&Pb[(cb * 16 + l16) * 64 +
                                        (((s * 4 + quad) ^ keyp) << 3)];
        rc = MFMA16(qv4[s], pf, rc);
      }
      if (quad == 0) Rs[64 * 68 + cb * 16 + l16] = (__bf16)rc[0];
    }
    __builtin_amdgcn_s_setprio(0);
    __syncthreads();

    // ---- gather shifted pos, no-max softmax, stash P (swizzled, alias Pb).
    // delta = j0-i0 decides the branch uniformly per tile:
    //   delta in {0,64}: ji==1 possible -> full per-element logic (2 tiles)
    //   delta >= 128: ji>=2 always -> row +1; delta <= -64: ji<=0 -> row +0.
    const int delta = j0 - i0;
    if (delta == 0 || delta == 64) {
#pragma unroll
      for (int r = 0; r < 4; ++r) {
#pragma unroll
        for (int cb = 0; cb < 4; ++cb) {
          const int di = rbase + r;
          const int dj = cb * 16 + l16;
          const int ji = delta + dj - di;
          float pos = 0.f;
          if (ji != 1) pos = (float)Rs[(di + (ji >= 2 ? 1 : 0)) * 68 + dj];
          const float w_ = exp2f((sA[cb][r] + pos) * SCALE2);
          lrun[r] += w_;
          Pa[di * 64 + (dj & 7) + ((((dj >> 3) ^ di) & 7) << 3)] = (__bf16)w_;
        }
      }
    } else {
      const int cadd = (delta >= 128) ? 1 : 0;
#pragma unroll
      for (int r = 0; r < 4; ++r) {
#pragma unroll
        for (int cb = 0; cb < 4; ++cb) {
          const int di = rbase + r;
          const int dj = cb * 16 + l16;
          const float pos = (float)Rs[(di + cadd) * 68 + dj];
          const float w_ = exp2f((sA[cb][r] + pos) * SCALE2);
          lrun[r] += w_;
          Pa[di * 64 + (dj & 7) + ((((dj >> 3) ^ di) & 7) << 3)] = (__bf16)w_;
        }
      }
    }

    // ---- O += Pa @ V (wave-local rows; in-wave LDS ordering suffices) ----
    __builtin_amdgcn_s_setprio(1);
#pragma unroll
    for (int s = 0; s < 2; ++s) {
      bf16x8 ap = *(const bf16x8*)&Pa[(wave * 16 + l16) * 64 +
                                      (((s * 4 + quad) ^ keyr) << 3)];
#pragma unroll
      for (int cb = 0; cb < 4; ++cb) {
        bf16x8 bv = *(const bf16x8*)&Vt[(cb * 16 + l16) * 64 +
                                        (((s * 4 + quad) ^ keyr) << 3)];
        Oacc[cb] = MFMA16(ap, bv, Oacc[cb]);
      }
    }
    __builtin_amdgcn_s_setprio(0);
  }

  // ---- epilogue: reduce l over 16 lanes, normalize, store ctx SWIZZLED ----
  float inv[4];
#pragma unroll
  for (int r = 0; r < 4; ++r) {
    float L = lrun[r];
    L += __shfl_xor(L, 1);
    L += __shfl_xor(L, 2);
    L += __shfl_xor(L, 4);
    L += __shfl_xor(L, 8);
    inv[r] = 1.f / L;
  }
  const int b = bhq >> 3, h = bhq & 7;
#pragma unroll
  for (int cb = 0; cb < 4; ++cb)
#pragma unroll
    for (int r = 0; r < 4; ++r) {
      const int row = i0 + rbase + r;
      const int chunk = cb * 2 + (l16 >> 3);
      const int col = h * DK_ + ((chunk ^ (row & 7)) << 3) + (l16 & 7);
      ctx[((size_t)(b * T_ + row)) * D_ + col] = (__bf16)(Oacc[cb][r] * inv[r]);
    }
}

// ---------------------------------------------------------------------------
extern "C" void kernel_launch(void* const* d_in, const int* in_sizes, int n_in,
                              void* d_out, int out_size, void* d_ws,
                              size_t ws_size, hipStream_t stream) {
  const float* query = (const float*)d_in[0];
  const float* key   = (const float*)d_in[1];
  const float* value = (const float*)d_in[2];
  const float* pos   = (const float*)d_in[3];
  const float* Wq = (const float*)d_in[4];
  const float* bq = (const float*)d_in[5];
  const float* Wk = (const float*)d_in[6];
  const float* bk = (const float*)d_in[7];
  const float* Wv = (const float*)d_in[8];
  const float* bv = (const float*)d_in[9];
  const float* Wp = (const float*)d_in[10];
  const float* ub = (const float*)d_in[11];
  const float* vbias = (const float*)d_in[12];
  const float* Wo = (const float*)d_in[13];
  const float* bo = (const float*)d_in[14];
  float* out = (float*)d_out;

  // ws: quB,qvB,kB,pB,vT,ctx (6 x 8MB) | Wt (2.5MB).
  char* ws = (char*)d_ws;
  const size_t ACT = (size_t)8192 * 512 * 2;  // 8 MB
  __bf16* quB = (__bf16*)ws;
  __bf16* qvB = (__bf16*)(ws + 1 * ACT);
  __bf16* kB  = (__bf16*)(ws + 2 * ACT);
  __bf16* pB  = (__bf16*)(ws + 3 * ACT);
  __bf16* vT  = (__bf16*)(ws + 4 * ACT);
  __bf16* ctx = (__bf16*)(ws + 5 * ACT);
  __bf16* Wt  = (__bf16*)(ws + 6 * ACT);      // 5 x 512 KB

  cvt_w<<<dim3(8, 8, 5), 256, 0, stream>>>(Wq, Wk, Wv, Wp, Wo, Wt);

  gemm_dma<<<dim3(64, 4, 4), 256, 0, stream>>>(
      query, key, value, pos, Wt, bq, bk, bv, ub, vbias,
      quB, qvB, kB, vT, pB);

  attn_mfma<<<dim3(1024), 256, 0, stream>>>(quB, qvB, kB, vT, pB, ctx);

  gemm_out<<<dim3(128, 4), 256, 0, stream>>>(ctx, Wt + 4 * 262144, bo, out);
}